// Round 3
// baseline (572.525 us; speedup 1.0000x reference)
//
#include <hip/hip_runtime.h>
#include <cstdint>

// ---------------------------------------------------------------------------
// EncoderLayer (B=4, S=2048, D=768, H=12, FF=3072) on MI355X / gfx950.
// bf16 MFMA everywhere; attention uses swapped QK^T + in-register softmax.
// ---------------------------------------------------------------------------

typedef __bf16 bf16_t;
typedef __bf16 bf16x8 __attribute__((ext_vector_type(8)));
typedef __bf16 bf16x4 __attribute__((ext_vector_type(4)));
typedef float  f32x4  __attribute__((ext_vector_type(4)));

#define NEGF (-1e30f)
#define LOG2E 1.44269504088896340736f

__device__ __forceinline__ float exp2_fast(float x) {
  float r;
  asm("v_exp_f32 %0, %1" : "=v"(r) : "v"(x));
  return r;
}

__device__ __forceinline__ f32x4 mfma16(bf16x8 a, bf16x8 b, f32x4 c) {
  return __builtin_amdgcn_mfma_f32_16x16x32_bf16(a, b, c, 0, 0, 0);
}

__device__ __forceinline__ void gload16(const bf16_t* gsrc, bf16_t* lds) {
  __builtin_amdgcn_global_load_lds(
      (const __attribute__((address_space(1))) unsigned int*)(uintptr_t)gsrc,
      (__attribute__((address_space(3))) unsigned int*)(uintptr_t)lds,
      16, 0, 0);
}

// ---------------------------------------------------------------------------
// Weight prep: Wt[n*K+k] = W[k*N+n] * scale, fp32 -> bf16
// ---------------------------------------------------------------------------
__global__ __launch_bounds__(256) void transpose_conv(
    const float* __restrict__ W, bf16_t* __restrict__ Wt, int K, int N, float scale)
{
  __shared__ float tile[32][33];
  const int n0 = blockIdx.x * 32, k0 = blockIdx.y * 32;
  const int tx = threadIdx.x, ty = threadIdx.y;
#pragma unroll
  for (int i = 0; i < 32; i += 8)
    tile[ty + i][tx] = W[(size_t)(k0 + ty + i) * N + n0 + tx];
  __syncthreads();
#pragma unroll
  for (int i = 0; i < 32; i += 8)
    Wt[(size_t)(n0 + ty + i) * K + k0 + tx] = (bf16_t)(tile[tx][ty + i] * scale);
}

// ---------------------------------------------------------------------------
// Mask pack: int32 [B,S,S] -> bits [B,S,S/32] (bit=1 means masked)
// ---------------------------------------------------------------------------
__global__ __launch_bounds__(256) void pack_mask(
    const int* __restrict__ mask, unsigned int* __restrict__ bits)
{
  const int gid = blockIdx.x * 256 + threadIdx.x;
  unsigned long long bal = __ballot(mask[gid] != 0);
  if ((threadIdx.x & 63) == 0) {
    const int wbase = gid >> 5;
    bits[wbase]     = (unsigned int)bal;
    bits[wbase + 1] = (unsigned int)(bal >> 32);
  }
}

// ---------------------------------------------------------------------------
// LayerNorm: fp32 [8192,768] -> bf16 [8192,768]
// ---------------------------------------------------------------------------
__global__ __launch_bounds__(256) void ln_kernel(
    const float* __restrict__ xin, const float* __restrict__ gamma,
    const float* __restrict__ beta, bf16_t* __restrict__ outb)
{
  __shared__ float red[8];
  const int row = blockIdx.x;
  const float* xr = xin + (size_t)row * 768;
  const int t = threadIdx.x;
  float v0 = xr[t], v1 = xr[t + 256], v2 = xr[t + 512];
  float s  = v0 + v1 + v2;
  float s2 = v0 * v0 + v1 * v1 + v2 * v2;
#pragma unroll
  for (int m = 32; m >= 1; m >>= 1) {
    s  += __shfl_xor(s, m, 64);
    s2 += __shfl_xor(s2, m, 64);
  }
  if ((t & 63) == 0) { red[t >> 6] = s; red[4 + (t >> 6)] = s2; }
  __syncthreads();
  s  = red[0] + red[1] + red[2] + red[3];
  s2 = red[4] + red[5] + red[6] + red[7];
  const float mu  = s * (1.0f / 768.0f);
  const float var = s2 * (1.0f / 768.0f) - mu * mu;
  const float rs  = rsqrtf(var + 1e-5f);
  bf16_t* orow = outb + (size_t)row * 768;
  orow[t]       = (bf16_t)((v0 - mu) * rs * gamma[t]       + beta[t]);
  orow[t + 256] = (bf16_t)((v1 - mu) * rs * gamma[t + 256] + beta[t + 256]);
  orow[t + 512] = (bf16_t)((v2 - mu) * rs * gamma[t + 512] + beta[t + 512]);
}

// ---------------------------------------------------------------------------
// GEMM: C[M,N] = A[M,K] @ Bt[N,K]^T  (128x128 tile, BK=32, 4 waves)
// ---------------------------------------------------------------------------
template <bool RELU, bool OUT_F32, bool HAS_BIAS, bool HAS_RES>
__global__ __launch_bounds__(256) void gemm_kernel(
    const bf16_t* __restrict__ A, const bf16_t* __restrict__ Bt,
    void* __restrict__ Cout, const float* __restrict__ bias,
    const float* __restrict__ res, int Mdim, int Ndim, int Kdim)
{
  __shared__ __align__(16) bf16_t As[128 * 32];
  __shared__ __align__(16) bf16_t Bs[128 * 32];
  const int tid = threadIdx.x;
  const int lane = tid & 63, w = tid >> 6;
  const int l15 = lane & 15, g = lane >> 4;
  const int bm = blockIdx.y * 128, bn = blockIdx.x * 128;
  const int wr = (w >> 1) * 64, wc = (w & 1) * 64;

  f32x4 acc[4][4] = {};
  const int nK = Kdim >> 5;
  for (int kt = 0; kt < nK; ++kt) {
    const int k0 = kt << 5;
#pragma unroll
    for (int it = 0; it < 2; ++it) {
      const int ch = it * 256 + tid;
      const int r = ch >> 2, cc = ch & 3;
      gload16(A  + (size_t)(bm + r) * Kdim + k0 + cc * 8, As + ch * 8);
      gload16(Bt + (size_t)(bn + r) * Kdim + k0 + cc * 8, Bs + ch * 8);
    }
    __syncthreads();
    bf16x8 af[4], bfr[4];
#pragma unroll
    for (int i = 0; i < 4; ++i)
      af[i] = *(const bf16x8*)(As + (wr + i * 16 + l15) * 32 + g * 8);
#pragma unroll
    for (int j = 0; j < 4; ++j)
      bfr[j] = *(const bf16x8*)(Bs + (wc + j * 16 + l15) * 32 + g * 8);
#pragma unroll
    for (int i = 0; i < 4; ++i)
#pragma unroll
      for (int j = 0; j < 4; ++j)
        acc[i][j] = mfma16(af[i], bfr[j], acc[i][j]);
    __syncthreads();
  }

#pragma unroll
  for (int i = 0; i < 4; ++i) {
#pragma unroll
    for (int j = 0; j < 4; ++j) {
      const int col = bn + wc + j * 16 + l15;
#pragma unroll
      for (int r = 0; r < 4; ++r) {
        const int row = bm + wr + i * 16 + g * 4 + r;
        float v = acc[i][j][r];
        if constexpr (HAS_BIAS) v += bias[col];
        if constexpr (HAS_RES)  v += res[(size_t)row * Ndim + col];
        if constexpr (RELU)     v = fmaxf(v, 0.f);
        if constexpr (OUT_F32)
          ((float*)Cout)[(size_t)row * Ndim + col] = v;
        else
          ((bf16_t*)Cout)[(size_t)row * Ndim + col] = (bf16_t)v;
      }
    }
  }
}

// ---------------------------------------------------------------------------
// V transpose: qkv v-columns -> vT[(bh*64+d)][s]
// ---------------------------------------------------------------------------
__global__ __launch_bounds__(256) void transpose_v(
    const bf16_t* __restrict__ qkv, bf16_t* __restrict__ vT)
{
  __shared__ bf16_t t[64][66];
  const int st = blockIdx.x;
  const int bh = blockIdx.y;
  const int b = bh / 12, h = bh % 12;
  const int tid = threadIdx.x;
#pragma unroll
  for (int it = 0; it < 2; ++it) {
    const int ch = it * 256 + tid;
    const int r = ch >> 3, c = ch & 7;
    bf16x8 vv = *(const bf16x8*)(qkv + (size_t)(b * 2048 + st * 64 + r) * 2304 +
                                 1536 + h * 64 + c * 8);
#pragma unroll
    for (int j = 0; j < 8; ++j) t[r][c * 8 + j] = vv[j];
  }
  __syncthreads();
#pragma unroll
  for (int it = 0; it < 2; ++it) {
    const int ch = it * 256 + tid;
    const int d = ch >> 3, c = ch & 7;
    bf16x8 o;
#pragma unroll
    for (int j = 0; j < 8; ++j) o[j] = t[c * 8 + j][d];
    *(bf16x8*)(vT + (size_t)(bh * 64 + d) * 2048 + st * 64 + c * 8) = o;
  }
}

// ---------------------------------------------------------------------------
// Flash attention, swapped-operand form. Block = (bh, qt), 4 waves x 32 q.
// S^T = mfma(K,Q): lane l15 = q, holds 32 k-scores in-register -> softmax is
// 31 VALU ops + 2 shuffles. P -> per-wave swizzled LDS (vector b64/b128).
// PV: O^T = mfma(V^T, P). K/V/Q read direct from L2 (no staging, no barriers).
// qkv's Q part is pre-scaled by log2(e)/sqrt(DH); softmax runs in exp2 domain.
// ---------------------------------------------------------------------------
__global__ __launch_bounds__(256, 2) void attn_kernel(
    const bf16_t* __restrict__ qkv, const bf16_t* __restrict__ vT,
    const unsigned int* __restrict__ mbits, bf16_t* __restrict__ ctx)
{
  __shared__ __align__(16) bf16_t Pb[4][2][16 * 128];
  const int tid = threadIdx.x;
  const int lane = tid & 63, w = tid >> 6;
  const int l15 = lane & 15, g = lane >> 4;
  const int bh = blockIdx.x;      // bh-major => XCD = bh % 8 (K/V L2 affinity)
  const int qt = blockIdx.y;
  const int b = bh / 12, h = bh % 12;
  const int qrow0 = qt * 128 + w * 32;          // wave's first q row

  // Q fragments: Q[q=qi*16+l15][d=kk*32+g*8+e]
  bf16x8 qf[2][2];
#pragma unroll
  for (int qi = 0; qi < 2; ++qi)
#pragma unroll
    for (int kk = 0; kk < 2; ++kk)
      qf[qi][kk] = *(const bf16x8*)(qkv +
          (size_t)(b * 2048 + qrow0 + qi * 16 + l15) * 2304 + h * 64 + kk * 32 + g * 8);

  f32x4 oacc[2][4] = {};
  float mrun[2] = {NEGF, NEGF}, lrun[2] = {0.f, 0.f};
  char* const pb0 = (char*)&Pb[w][0][0];
  char* const pb1 = (char*)&Pb[w][1][0];
  const int swz = l15 & 7;

  for (int kt = 0; kt < 16; ++kt) {
    const int kb = b * 2048 + kt * 128;
    // ---- S^T[k][q] = K @ Q^T : sacc[qi][tile], k = tile*16+g*4+reg ----
    f32x4 sacc[2][8] = {};
#pragma unroll
    for (int t = 0; t < 8; ++t) {
#pragma unroll
      for (int kk = 0; kk < 2; ++kk) {
        bf16x8 kf = *(const bf16x8*)(qkv +
            (size_t)(kb + t * 16 + l15) * 2304 + 768 + h * 64 + kk * 32 + g * 8);
        sacc[0][t] = mfma16(kf, qf[0][kk], sacc[0][t]);
        sacc[1][t] = mfma16(kf, qf[1][kk], sacc[1][t]);
      }
    }

    // ---- mask + online softmax (log2 domain) + P store ----
#pragma unroll
    for (int qi = 0; qi < 2; ++qi) {
      const int qabs = qrow0 + qi * 16 + l15;
      const uint4 mm = *(const uint4*)(mbits + (size_t)(b * 2048 + qabs) * 64 + kt * 4);
      const unsigned mw[4] = {mm.x, mm.y, mm.z, mm.w};
      float rmax = NEGF;
#pragma unroll
      for (int t = 0; t < 8; ++t) {
        const unsigned sel = mw[t >> 1] >> ((t & 1) * 16 + g * 4);
#pragma unroll
        for (int r = 0; r < 4; ++r) {
          const float sv = ((sel >> r) & 1u) ? NEGF : sacc[qi][t][r];
          sacc[qi][t][r] = sv;
          rmax = fmaxf(rmax, sv);
        }
      }
      rmax = fmaxf(rmax, __shfl_xor(rmax, 16, 64));
      rmax = fmaxf(rmax, __shfl_xor(rmax, 32, 64));
      const float mn = fmaxf(mrun[qi], rmax);
      const float sc = exp2_fast(mrun[qi] - mn);
      float ps = 0.f;
#pragma unroll
      for (int t = 0; t < 8; ++t)
#pragma unroll
        for (int r = 0; r < 4; ++r) {
          const float sv = sacc[qi][t][r];
          const float p = (sv < -1e29f) ? 0.f : exp2_fast(sv - mn);
          sacc[qi][t][r] = p;
          ps += p;
        }
      ps += __shfl_xor(ps, 16, 64);
      ps += __shfl_xor(ps, 32, 64);
      mrun[qi] = mn;
      lrun[qi] = lrun[qi] * sc + ps;
#pragma unroll
      for (int jd = 0; jd < 4; ++jd) oacc[qi][jd] *= sc;
      // pack 4 bf16 per tile, store 8B to swizzled per-wave LDS
      char* const pb = qi ? pb1 : pb0;
#pragma unroll
      for (int t = 0; t < 8; ++t) {
        bf16x4 pk = {(bf16_t)sacc[qi][t][0], (bf16_t)sacc[qi][t][1],
                     (bf16_t)sacc[qi][t][2], (bf16_t)sacc[qi][t][3]};
        const int chunk = (t * 2 + (g >> 1)) ^ swz;
        *(bf16x4*)(pb + l15 * 256 + chunk * 16 + (g & 1) * 8) = pk;
      }
    }

    // ---- O^T[d][q] += V^T @ P : A = V^T rows d, B = P[q][k] ----
#pragma unroll
    for (int ks = 0; ks < 4; ++ks) {
      const int rch = (ks * 4 + g) ^ swz;
      bf16x8 pa0 = *(const bf16x8*)(pb0 + l15 * 256 + rch * 16);
      bf16x8 pa1 = *(const bf16x8*)(pb1 + l15 * 256 + rch * 16);
#pragma unroll
      for (int jd = 0; jd < 4; ++jd) {
        bf16x8 vf = *(const bf16x8*)(vT +
            (size_t)(bh * 64 + jd * 16 + l15) * 2048 + kt * 128 + ks * 32 + g * 8);
        oacc[0][jd] = mfma16(vf, pa0, oacc[0][jd]);
        oacc[1][jd] = mfma16(vf, pa1, oacc[1][jd]);
      }
    }
  }

  // ---- normalize + write ctx: lane holds O^T[d=jd*16+g*4+r][q=qi*16+l15] ----
#pragma unroll
  for (int qi = 0; qi < 2; ++qi) {
    const float l = lrun[qi];
    const float inv = (l > 0.f) ? 1.f / l : 0.f;
    const int qabs = qrow0 + qi * 16 + l15;
    bf16_t* crow = ctx + (size_t)(b * 2048 + qabs) * 768 + h * 64;
#pragma unroll
    for (int jd = 0; jd < 4; ++jd) {
      bf16x4 ov = {(bf16_t)(oacc[qi][jd][0] * inv), (bf16_t)(oacc[qi][jd][1] * inv),
                   (bf16_t)(oacc[qi][jd][2] * inv), (bf16_t)(oacc[qi][jd][3] * inv)};
      *(bf16x4*)(crow + jd * 16 + g * 4) = ov;
    }
  }
}

// ---------------------------------------------------------------------------
// Host launcher
// ---------------------------------------------------------------------------
extern "C" void kernel_launch(void* const* d_in, const int* in_sizes, int n_in,
                              void* d_out, int out_size, void* d_ws, size_t ws_size,
                              hipStream_t stream) {
  const float* x  = (const float*)d_in[0];
  const int* mask = (const int*)d_in[1];
  const float* wq = (const float*)d_in[2];
  const float* wk = (const float*)d_in[3];
  const float* wv = (const float*)d_in[4];
  const float* wo = (const float*)d_in[5];
  const float* bo = (const float*)d_in[6];
  const float* w1 = (const float*)d_in[7];
  const float* w2 = (const float*)d_in[8];
  const float* g1 = (const float*)d_in[9];
  const float* b1 = (const float*)d_in[10];
  const float* g2 = (const float*)d_in[11];
  const float* b2 = (const float*)d_in[12];
  float* out = (float*)d_out;

  char* p = (char*)d_ws;
  bf16_t* WQKVT = (bf16_t*)p; p += (size_t)2304 * 768 * 2;
  bf16_t* WOT   = (bf16_t*)p; p += (size_t)768 * 768 * 2;
  bf16_t* W1T   = (bf16_t*)p; p += (size_t)3072 * 768 * 2;
  bf16_t* W2T   = (bf16_t*)p; p += (size_t)768 * 3072 * 2;
  unsigned int* MB = (unsigned int*)p; p += (size_t)4 * 2048 * 64 * 4;
  bf16_t* Hbuf  = (bf16_t*)p; p += (size_t)8192 * 768 * 2;
  float*  X2    = (float*)p;  p += (size_t)8192 * 768 * 4;
  bf16_t* QKV   = (bf16_t*)p; p += (size_t)8192 * 2304 * 2;
  bf16_t* CTX   = (bf16_t*)p;
  bf16_t* FFN   = QKV;
  bf16_t* VT    = Hbuf;

  const dim3 tb(32, 8);
  // wq carries 1/sqrt(DH) * log2(e) so softmax runs in exp2 domain
  transpose_conv<<<dim3(24, 24), tb, 0, stream>>>(wq, WQKVT,              768, 768, 0.125f * LOG2E);
  transpose_conv<<<dim3(24, 24), tb, 0, stream>>>(wk, WQKVT + 768 * 768,  768, 768, 1.f);
  transpose_conv<<<dim3(24, 24), tb, 0, stream>>>(wv, WQKVT + 1536 * 768, 768, 768, 1.f);
  transpose_conv<<<dim3(24, 24), tb, 0, stream>>>(wo, WOT, 768, 768, 1.f);
  transpose_conv<<<dim3(96, 24), tb, 0, stream>>>(w1, W1T, 768, 3072, 1.f);
  transpose_conv<<<dim3(24, 96), tb, 0, stream>>>(w2, W2T, 3072, 768, 1.f);
  pack_mask<<<65536, 256, 0, stream>>>(mask, MB);

  ln_kernel<<<8192, 256, 0, stream>>>(x, g1, b1, Hbuf);
  gemm_kernel<false, false, false, false><<<dim3(18, 64), 256, 0, stream>>>(
      Hbuf, WQKVT, QKV, nullptr, nullptr, 8192, 2304, 768);
  transpose_v<<<dim3(32, 48), 256, 0, stream>>>(QKV, VT);
  attn_kernel<<<dim3(48, 16), 256, 0, stream>>>(QKV, VT, MB, CTX);
  gemm_kernel<false, true, true, true><<<dim3(6, 64), 256, 0, stream>>>(
      CTX, WOT, X2, bo, x, 8192, 768, 768);

  ln_kernel<<<8192, 256, 0, stream>>>(X2, g2, b2, Hbuf);
  gemm_kernel<true, false, false, false><<<dim3(24, 64), 256, 0, stream>>>(
      Hbuf, W1T, FFN, nullptr, nullptr, 8192, 3072, 768);
  gemm_kernel<false, true, false, true><<<dim3(6, 64), 256, 0, stream>>>(
      FFN, W2T, out, nullptr, X2, 8192, 768, 3072);
}

// Round 4
// 422.369 us; speedup vs baseline: 1.3555x; 1.3555x over previous
//
#include <hip/hip_runtime.h>
#include <cstdint>

// ---------------------------------------------------------------------------
// EncoderLayer (B=4, S=2048, D=768, H=12, FF=3072) on MI355X / gfx950.
// bf16 MFMA everywhere; attention: staged K/V (double-buffered, 2-phase
// pipeline) + swapped QK^T with in-register softmax.
// ---------------------------------------------------------------------------

typedef __bf16 bf16_t;
typedef __bf16 bf16x8 __attribute__((ext_vector_type(8)));
typedef __bf16 bf16x4 __attribute__((ext_vector_type(4)));
typedef float  f32x4  __attribute__((ext_vector_type(4)));

#define NEGF (-1e30f)
#define LOG2E 1.44269504088896340736f

__device__ __forceinline__ float exp2_fast(float x) {
  float r;
  asm("v_exp_f32 %0, %1" : "=v"(r) : "v"(x));
  return r;
}

__device__ __forceinline__ f32x4 mfma16(bf16x8 a, bf16x8 b, f32x4 c) {
  return __builtin_amdgcn_mfma_f32_16x16x32_bf16(a, b, c, 0, 0, 0);
}

__device__ __forceinline__ void gload16(const bf16_t* gsrc, bf16_t* lds) {
  __builtin_amdgcn_global_load_lds(
      (const __attribute__((address_space(1))) unsigned int*)(uintptr_t)gsrc,
      (__attribute__((address_space(3))) unsigned int*)(uintptr_t)lds,
      16, 0, 0);
}

// ---------------------------------------------------------------------------
// Weight prep: Wt[n*K+k] = W[k*N+n] * scale, fp32 -> bf16
// ---------------------------------------------------------------------------
__global__ __launch_bounds__(256) void transpose_conv(
    const float* __restrict__ W, bf16_t* __restrict__ Wt, int K, int N, float scale)
{
  __shared__ float tile[32][33];
  const int n0 = blockIdx.x * 32, k0 = blockIdx.y * 32;
  const int tx = threadIdx.x, ty = threadIdx.y;
#pragma unroll
  for (int i = 0; i < 32; i += 8)
    tile[ty + i][tx] = W[(size_t)(k0 + ty + i) * N + n0 + tx];
  __syncthreads();
#pragma unroll
  for (int i = 0; i < 32; i += 8)
    Wt[(size_t)(n0 + ty + i) * K + k0 + tx] = (bf16_t)(tile[tx][ty + i] * scale);
}

// ---------------------------------------------------------------------------
// Mask pack: int32 [B,S,S] -> bits [B,S,S/32] (bit=1 means masked)
// ---------------------------------------------------------------------------
__global__ __launch_bounds__(256) void pack_mask(
    const int* __restrict__ mask, unsigned int* __restrict__ bits)
{
  const int gid = blockIdx.x * 256 + threadIdx.x;
  unsigned long long bal = __ballot(mask[gid] != 0);
  if ((threadIdx.x & 63) == 0) {
    const int wbase = gid >> 5;
    bits[wbase]     = (unsigned int)bal;
    bits[wbase + 1] = (unsigned int)(bal >> 32);
  }
}

// ---------------------------------------------------------------------------
// LayerNorm: fp32 [8192,768] -> bf16 [8192,768]
// ---------------------------------------------------------------------------
__global__ __launch_bounds__(256) void ln_kernel(
    const float* __restrict__ xin, const float* __restrict__ gamma,
    const float* __restrict__ beta, bf16_t* __restrict__ outb)
{
  __shared__ float red[8];
  const int row = blockIdx.x;
  const float* xr = xin + (size_t)row * 768;
  const int t = threadIdx.x;
  float v0 = xr[t], v1 = xr[t + 256], v2 = xr[t + 512];
  float s  = v0 + v1 + v2;
  float s2 = v0 * v0 + v1 * v1 + v2 * v2;
#pragma unroll
  for (int m = 32; m >= 1; m >>= 1) {
    s  += __shfl_xor(s, m, 64);
    s2 += __shfl_xor(s2, m, 64);
  }
  if ((t & 63) == 0) { red[t >> 6] = s; red[4 + (t >> 6)] = s2; }
  __syncthreads();
  s  = red[0] + red[1] + red[2] + red[3];
  s2 = red[4] + red[5] + red[6] + red[7];
  const float mu  = s * (1.0f / 768.0f);
  const float var = s2 * (1.0f / 768.0f) - mu * mu;
  const float rs  = rsqrtf(var + 1e-5f);
  bf16_t* orow = outb + (size_t)row * 768;
  orow[t]       = (bf16_t)((v0 - mu) * rs * gamma[t]       + beta[t]);
  orow[t + 256] = (bf16_t)((v1 - mu) * rs * gamma[t + 256] + beta[t + 256]);
  orow[t + 512] = (bf16_t)((v2 - mu) * rs * gamma[t + 512] + beta[t + 512]);
}

// ---------------------------------------------------------------------------
// GEMM: C[M,N] = A[M,K] @ Bt[N,K]^T  (128x128 tile, BK=32, 4 waves)
// ---------------------------------------------------------------------------
template <bool RELU, bool OUT_F32, bool HAS_BIAS, bool HAS_RES>
__global__ __launch_bounds__(256) void gemm_kernel(
    const bf16_t* __restrict__ A, const bf16_t* __restrict__ Bt,
    void* __restrict__ Cout, const float* __restrict__ bias,
    const float* __restrict__ res, int Mdim, int Ndim, int Kdim)
{
  __shared__ __align__(16) bf16_t As[128 * 32];
  __shared__ __align__(16) bf16_t Bs[128 * 32];
  const int tid = threadIdx.x;
  const int lane = tid & 63, w = tid >> 6;
  const int l15 = lane & 15, g = lane >> 4;
  const int bm = blockIdx.y * 128, bn = blockIdx.x * 128;
  const int wr = (w >> 1) * 64, wc = (w & 1) * 64;

  f32x4 acc[4][4] = {};
  const int nK = Kdim >> 5;
  for (int kt = 0; kt < nK; ++kt) {
    const int k0 = kt << 5;
#pragma unroll
    for (int it = 0; it < 2; ++it) {
      const int ch = it * 256 + tid;
      const int r = ch >> 2, cc = ch & 3;
      gload16(A  + (size_t)(bm + r) * Kdim + k0 + cc * 8, As + ch * 8);
      gload16(Bt + (size_t)(bn + r) * Kdim + k0 + cc * 8, Bs + ch * 8);
    }
    __syncthreads();
    bf16x8 af[4], bfr[4];
#pragma unroll
    for (int i = 0; i < 4; ++i)
      af[i] = *(const bf16x8*)(As + (wr + i * 16 + l15) * 32 + g * 8);
#pragma unroll
    for (int j = 0; j < 4; ++j)
      bfr[j] = *(const bf16x8*)(Bs + (wc + j * 16 + l15) * 32 + g * 8);
#pragma unroll
    for (int i = 0; i < 4; ++i)
#pragma unroll
      for (int j = 0; j < 4; ++j)
        acc[i][j] = mfma16(af[i], bfr[j], acc[i][j]);
    __syncthreads();
  }

#pragma unroll
  for (int i = 0; i < 4; ++i) {
#pragma unroll
    for (int j = 0; j < 4; ++j) {
      const int col = bn + wc + j * 16 + l15;
#pragma unroll
      for (int r = 0; r < 4; ++r) {
        const int row = bm + wr + i * 16 + g * 4 + r;
        float v = acc[i][j][r];
        if constexpr (HAS_BIAS) v += bias[col];
        if constexpr (HAS_RES)  v += res[(size_t)row * Ndim + col];
        if constexpr (RELU)     v = fmaxf(v, 0.f);
        if constexpr (OUT_F32)
          ((float*)Cout)[(size_t)row * Ndim + col] = v;
        else
          ((bf16_t*)Cout)[(size_t)row * Ndim + col] = (bf16_t)v;
      }
    }
  }
}

// ---------------------------------------------------------------------------
// V transpose: qkv v-columns -> vT[(bh*64+d)][s]
// ---------------------------------------------------------------------------
__global__ __launch_bounds__(256) void transpose_v(
    const bf16_t* __restrict__ qkv, bf16_t* __restrict__ vT)
{
  __shared__ bf16_t t[64][66];
  const int st = blockIdx.x;
  const int bh = blockIdx.y;
  const int b = bh / 12, h = bh % 12;
  const int tid = threadIdx.x;
#pragma unroll
  for (int it = 0; it < 2; ++it) {
    const int ch = it * 256 + tid;
    const int r = ch >> 3, c = ch & 7;
    bf16x8 vv = *(const bf16x8*)(qkv + (size_t)(b * 2048 + st * 64 + r) * 2304 +
                                 1536 + h * 64 + c * 8);
#pragma unroll
    for (int j = 0; j < 8; ++j) t[r][c * 8 + j] = vv[j];
  }
  __syncthreads();
#pragma unroll
  for (int it = 0; it < 2; ++it) {
    const int ch = it * 256 + tid;
    const int d = ch >> 3, c = ch & 7;
    bf16x8 o;
#pragma unroll
    for (int j = 0; j < 8; ++j) o[j] = t[c * 8 + j][d];
    *(bf16x8*)(vT + (size_t)(bh * 64 + d) * 2048 + st * 64 + c * 8) = o;
  }
}

// ---------------------------------------------------------------------------
// Flash attention. Block = (bh, qt), 4 waves x 32 q rows.
// K/V staged in double-buffered LDS via global_load_lds (swizzled source);
// next tile prefetch issued before current tile's compute; ONE barrier per kt.
// S^T = mfma(K,Q): lane holds 32 k-scores of one q row -> in-register softmax.
// P -> per-wave swizzled LDS (vector writes). PV: O^T = mfma(V^T, P).
// qkv's Q part pre-scaled by log2(e)/sqrt(DH); softmax in exp2 domain.
// ---------------------------------------------------------------------------
__global__ __launch_bounds__(256, 2) void attn_kernel(
    const bf16_t* __restrict__ qkv, const bf16_t* __restrict__ vT,
    const unsigned int* __restrict__ mbits, bf16_t* __restrict__ ctx)
{
  __shared__ __align__(16) bf16_t KsBuf[2][128 * 64];   // [s=128][d=64], swizzled
  __shared__ __align__(16) bf16_t VsBuf[2][64 * 128];   // [d=64][s=128], swizzled
  __shared__ __align__(16) bf16_t Pb[4][2][16 * 128];
  const int tid = threadIdx.x;
  const int lane = tid & 63, w = tid >> 6;
  const int l15 = lane & 15, g = lane >> 4;
  const int bh = blockIdx.x;      // bh-major => XCD = bh % 8 (K/V L2 affinity)
  const int qt = blockIdx.y;
  const int b = bh / 12, h = bh % 12;
  const int qrow0 = qt * 128 + w * 32;

  // staging source offsets for this thread (same every kt)
  const int kch = tid;                       // K: thread handles chunks tid, tid+256, ...
  // Q fragments direct from global: Q[q=qi*16+l15][d=kk*32+g*8+e]
  bf16x8 qf[2][2];
#pragma unroll
  for (int qi = 0; qi < 2; ++qi)
#pragma unroll
    for (int kk = 0; kk < 2; ++kk)
      qf[qi][kk] = *(const bf16x8*)(qkv +
          (size_t)(b * 2048 + qrow0 + qi * 16 + l15) * 2304 + h * 64 + kk * 32 + g * 8);

  // ---- staging helper: stage K tile kt into ks, V^T tile kt into vs ----
  auto stage = [&](bf16_t* ks, bf16_t* vs, int kt) {
    const size_t kb = (size_t)(b * 2048 + kt * 128);
#pragma unroll
    for (int it = 0; it < 4; ++it) {
      const int ch = it * 256 + kch;         // 0..1023
      const int r = ch >> 3, c = ch & 7;     // K row (s), 16B chunk
      gload16(qkv + (kb + r) * 2304 + 768 + h * 64 + ((c ^ (r & 7)) * 8), ks + ch * 8);
    }
#pragma unroll
    for (int it = 0; it < 4; ++it) {
      const int ch = it * 256 + kch;
      const int r = ch >> 4, c = ch & 15;    // V^T row (d), 16B chunk
      gload16(vT + (size_t)(bh * 64 + r) * 2048 + kt * 128 + ((c ^ (r & 7)) * 8),
              vs + ch * 8);
    }
  };

  f32x4 oacc[2][4] = {};
  float mrun[2] = {NEGF, NEGF}, lrun[2] = {0.f, 0.f};
  char* const pb0 = (char*)&Pb[w][0][0];
  char* const pb1 = (char*)&Pb[w][1][0];
  const int swz = l15 & 7;

  // prologue: stage tile 0
  stage(KsBuf[0], VsBuf[0], 0);
  __syncthreads();

  for (int kt = 0; kt < 16; ++kt) {
    const bf16_t* ksc = (kt & 1) ? KsBuf[1] : KsBuf[0];
    const bf16_t* vsc = (kt & 1) ? VsBuf[1] : VsBuf[0];
    // prefetch next tile into the other buffer (completed by the barrier below)
    if (kt < 15)
      stage((kt & 1) ? KsBuf[0] : KsBuf[1], (kt & 1) ? VsBuf[0] : VsBuf[1], kt + 1);

    // prefetch masks for this tile
    uint4 mm[2];
#pragma unroll
    for (int qi = 0; qi < 2; ++qi)
      mm[qi] = *(const uint4*)(mbits +
          (size_t)(b * 2048 + qrow0 + qi * 16 + l15) * 64 + kt * 4);

    // ---- S^T[k][q] = K @ Q^T from LDS ----
    f32x4 sacc[2][8] = {};
#pragma unroll
    for (int t = 0; t < 8; ++t) {
      const int row = t * 16 + l15;
#pragma unroll
      for (int kk = 0; kk < 2; ++kk) {
        bf16x8 kf = *(const bf16x8*)(ksc + row * 64 + (((kk * 4 + g) ^ (l15 & 7)) * 8));
        sacc[0][t] = mfma16(kf, qf[0][kk], sacc[0][t]);
        sacc[1][t] = mfma16(kf, qf[1][kk], sacc[1][t]);
      }
    }

    // ---- mask + online softmax (exp2 domain) + P store ----
#pragma unroll
    for (int qi = 0; qi < 2; ++qi) {
      const unsigned mw[4] = {mm[qi].x, mm[qi].y, mm[qi].z, mm[qi].w};
      float rmax = NEGF;
#pragma unroll
      for (int t = 0; t < 8; ++t) {
        const unsigned sel = mw[t >> 1] >> ((t & 1) * 16 + g * 4);
#pragma unroll
        for (int r = 0; r < 4; ++r) {
          const float sv = ((sel >> r) & 1u) ? NEGF : sacc[qi][t][r];
          sacc[qi][t][r] = sv;
          rmax = fmaxf(rmax, sv);
        }
      }
      rmax = fmaxf(rmax, __shfl_xor(rmax, 16, 64));
      rmax = fmaxf(rmax, __shfl_xor(rmax, 32, 64));
      const float mn = fmaxf(mrun[qi], rmax);
      const float sc = exp2_fast(mrun[qi] - mn);
      float ps = 0.f;
#pragma unroll
      for (int t = 0; t < 8; ++t)
#pragma unroll
        for (int r = 0; r < 4; ++r) {
          const float p = exp2_fast(sacc[qi][t][r] - mn);  // exp2(-1e30-mn)=0
          sacc[qi][t][r] = p;
          ps += p;
        }
      ps += __shfl_xor(ps, 16, 64);
      ps += __shfl_xor(ps, 32, 64);
      mrun[qi] = mn;
      lrun[qi] = lrun[qi] * sc + ps;
#pragma unroll
      for (int jd = 0; jd < 4; ++jd) oacc[qi][jd] *= sc;
      char* const pb = qi ? pb1 : pb0;
#pragma unroll
      for (int t = 0; t < 8; ++t) {
        bf16x4 pk = {(bf16_t)sacc[qi][t][0], (bf16_t)sacc[qi][t][1],
                     (bf16_t)sacc[qi][t][2], (bf16_t)sacc[qi][t][3]};
        const int chunk = (t * 2 + (g >> 1)) ^ swz;
        *(bf16x4*)(pb + l15 * 256 + chunk * 16 + (g & 1) * 8) = pk;
      }
    }

    // ---- O^T[d][q] += V^T @ P (V^T from LDS, P from per-wave LDS) ----
#pragma unroll
    for (int ks = 0; ks < 4; ++ks) {
      const int rch = (ks * 4 + g) ^ swz;
      bf16x8 pa0 = *(const bf16x8*)(pb0 + l15 * 256 + rch * 16);
      bf16x8 pa1 = *(const bf16x8*)(pb1 + l15 * 256 + rch * 16);
#pragma unroll
      for (int jd = 0; jd < 4; ++jd) {
        const int rv = jd * 16 + l15;
        bf16x8 vf = *(const bf16x8*)(vsc + rv * 128 + (((ks * 4 + g) ^ (l15 & 7)) * 8));
        oacc[0][jd] = mfma16(vf, pa0, oacc[0][jd]);
        oacc[1][jd] = mfma16(vf, pa1, oacc[1][jd]);
      }
    }
    // one barrier per kt: ensures (a) all waves done reading cur buffers,
    // (b) prefetch for kt+1 landed (implicit vmcnt(0) drain).
    __syncthreads();
  }

  // ---- normalize + write ctx: lane holds O^T[d=jd*16+g*4+r][q=qi*16+l15] ----
#pragma unroll
  for (int qi = 0; qi < 2; ++qi) {
    const float l = lrun[qi];
    const float inv = (l > 0.f) ? 1.f / l : 0.f;
    const int qabs = qrow0 + qi * 16 + l15;
    bf16_t* crow = ctx + (size_t)(b * 2048 + qabs) * 768 + h * 64;
#pragma unroll
    for (int jd = 0; jd < 4; ++jd) {
      bf16x4 ov = {(bf16_t)(oacc[qi][jd][0] * inv), (bf16_t)(oacc[qi][jd][1] * inv),
                   (bf16_t)(oacc[qi][jd][2] * inv), (bf16_t)(oacc[qi][jd][3] * inv)};
      *(bf16x4*)(crow + jd * 16 + g * 4) = ov;
    }
  }
}

// ---------------------------------------------------------------------------
// Host launcher
// ---------------------------------------------------------------------------
extern "C" void kernel_launch(void* const* d_in, const int* in_sizes, int n_in,
                              void* d_out, int out_size, void* d_ws, size_t ws_size,
                              hipStream_t stream) {
  const float* x  = (const float*)d_in[0];
  const int* mask = (const int*)d_in[1];
  const float* wq = (const float*)d_in[2];
  const float* wk = (const float*)d_in[3];
  const float* wv = (const float*)d_in[4];
  const float* wo = (const float*)d_in[5];
  const float* bo = (const float*)d_in[6];
  const float* w1 = (const float*)d_in[7];
  const float* w2 = (const float*)d_in[8];
  const float* g1 = (const float*)d_in[9];
  const float* b1 = (const float*)d_in[10];
  const float* g2 = (const float*)d_in[11];
  const float* b2 = (const float*)d_in[12];
  float* out = (float*)d_out;

  char* p = (char*)d_ws;
  bf16_t* WQKVT = (bf16_t*)p; p += (size_t)2304 * 768 * 2;
  bf16_t* WOT   = (bf16_t*)p; p += (size_t)768 * 768 * 2;
  bf16_t* W1T   = (bf16_t*)p; p += (size_t)3072 * 768 * 2;
  bf16_t* W2T   = (bf16_t*)p; p += (size_t)768 * 3072 * 2;
  unsigned int* MB = (unsigned int*)p; p += (size_t)4 * 2048 * 64 * 4;
  bf16_t* Hbuf  = (bf16_t*)p; p += (size_t)8192 * 768 * 2;
  float*  X2    = (float*)p;  p += (size_t)8192 * 768 * 4;
  bf16_t* QKV   = (bf16_t*)p; p += (size_t)8192 * 2304 * 2;
  bf16_t* CTX   = (bf16_t*)p;
  bf16_t* FFN   = QKV;
  bf16_t* VT    = Hbuf;

  const dim3 tb(32, 8);
  // wq carries 1/sqrt(DH) * log2(e) so softmax runs in exp2 domain
  transpose_conv<<<dim3(24, 24), tb, 0, stream>>>(wq, WQKVT,              768, 768, 0.125f * LOG2E);
  transpose_conv<<<dim3(24, 24), tb, 0, stream>>>(wk, WQKVT + 768 * 768,  768, 768, 1.f);
  transpose_conv<<<dim3(24, 24), tb, 0, stream>>>(wv, WQKVT + 1536 * 768, 768, 768, 1.f);
  transpose_conv<<<dim3(24, 24), tb, 0, stream>>>(wo, WOT, 768, 768, 1.f);
  transpose_conv<<<dim3(96, 24), tb, 0, stream>>>(w1, W1T, 768, 3072, 1.f);
  transpose_conv<<<dim3(24, 96), tb, 0, stream>>>(w2, W2T, 3072, 768, 1.f);
  pack_mask<<<65536, 256, 0, stream>>>(mask, MB);

  ln_kernel<<<8192, 256, 0, stream>>>(x, g1, b1, Hbuf);
  gemm_kernel<false, false, false, false><<<dim3(18, 64), 256, 0, stream>>>(
      Hbuf, WQKVT, QKV, nullptr, nullptr, 8192, 2304, 768);
  transpose_v<<<dim3(32, 48), 256, 0, stream>>>(QKV, VT);
  attn_kernel<<<dim3(48, 16), 256, 0, stream>>>(QKV, VT, MB, CTX);
  gemm_kernel<false, true, true, true><<<dim3(6, 64), 256, 0, stream>>>(
      CTX, WOT, X2, bo, x, 8192, 768, 768);

  ln_kernel<<<8192, 256, 0, stream>>>(X2, g2, b2, Hbuf);
  gemm_kernel<true, false, false, false><<<dim3(24, 64), 256, 0, stream>>>(
      Hbuf, W1T, FFN, nullptr, nullptr, 8192, 3072, 768);
  gemm_kernel<false, true, false, true><<<dim3(6, 64), 256, 0, stream>>>(
      FFN, W2T, out, nullptr, X2, 8192, 768, 3072);
}

// Round 5
// 366.308 us; speedup vs baseline: 1.5630x; 1.1530x over previous
//
#include <hip/hip_runtime.h>
#include <cstdint>

// ---------------------------------------------------------------------------
// EncoderLayer (B=4, S=2048, D=768, H=12, FF=3072) on MI355X / gfx950.
// bf16 MFMA everywhere. Attention: 32x32x16 MFMA, swapped QK^T, in-register
// softmax, P redistributed to PV B-fragments via v_permlane32_swap_b32
// (no P LDS buffer). K/V double-buffered in LDS, one barrier per k-tile.
// ---------------------------------------------------------------------------

typedef __bf16 bf16_t;
typedef __bf16 bf16x8 __attribute__((ext_vector_type(8)));
typedef __bf16 bf16x4 __attribute__((ext_vector_type(4)));
typedef __bf16 bf16x2 __attribute__((ext_vector_type(2)));
typedef float  f32x4  __attribute__((ext_vector_type(4)));
typedef float  f32x16 __attribute__((ext_vector_type(16)));

#define NEGF (-1e30f)
#define LOG2E 1.44269504088896340736f

__device__ __forceinline__ float exp2_fast(float x) {
  float r;
  asm("v_exp_f32 %0, %1" : "=v"(r) : "v"(x));
  return r;
}

__device__ __forceinline__ f32x4 mfma16(bf16x8 a, bf16x8 b, f32x4 c) {
  return __builtin_amdgcn_mfma_f32_16x16x32_bf16(a, b, c, 0, 0, 0);
}
__device__ __forceinline__ f32x16 mfma32(bf16x8 a, bf16x8 b, f32x16 c) {
  return __builtin_amdgcn_mfma_f32_32x32x16_bf16(a, b, c, 0, 0, 0);
}

__device__ __forceinline__ void gload16(const bf16_t* gsrc, bf16_t* lds) {
  __builtin_amdgcn_global_load_lds(
      (const __attribute__((address_space(1))) unsigned int*)(uintptr_t)gsrc,
      (__attribute__((address_space(3))) unsigned int*)(uintptr_t)lds,
      16, 0, 0);
}

// pack two f32 into a u32 of two bf16
__device__ __forceinline__ unsigned pk2(float a, float b) {
  bf16x2 v = {(bf16_t)a, (bf16_t)b};
  return __builtin_bit_cast(unsigned, v);
}
// a.hi_lanes := b.lo_lanes ; b.lo_lanes := a.hi_lanes (cross-half exchange)
__device__ __forceinline__ void pl32_swap(unsigned& a, unsigned& b) {
  asm("v_permlane32_swap_b32 %0, %1" : "+v"(a), "+v"(b));
}
__device__ __forceinline__ bf16x8 frag4(unsigned w0, unsigned w1,
                                        unsigned w2, unsigned w3) {
  union { unsigned u[4]; bf16x8 v; } t;
  t.u[0] = w0; t.u[1] = w1; t.u[2] = w2; t.u[3] = w3;
  return t.v;
}

// ---------------------------------------------------------------------------
// Weight prep: Wt[n*K+k] = W[k*N+n] * scale, fp32 -> bf16
// ---------------------------------------------------------------------------
__global__ __launch_bounds__(256) void transpose_conv(
    const float* __restrict__ W, bf16_t* __restrict__ Wt, int K, int N, float scale)
{
  __shared__ float tile[32][33];
  const int n0 = blockIdx.x * 32, k0 = blockIdx.y * 32;
  const int tx = threadIdx.x, ty = threadIdx.y;
#pragma unroll
  for (int i = 0; i < 32; i += 8)
    tile[ty + i][tx] = W[(size_t)(k0 + ty + i) * N + n0 + tx];
  __syncthreads();
#pragma unroll
  for (int i = 0; i < 32; i += 8)
    Wt[(size_t)(n0 + ty + i) * K + k0 + tx] = (bf16_t)(tile[tx][ty + i] * scale);
}

// ---------------------------------------------------------------------------
// Mask pack: int32 [B,S,S] -> bits [B,S,S/32] (bit=1 means masked)
// ---------------------------------------------------------------------------
__global__ __launch_bounds__(256) void pack_mask(
    const int* __restrict__ mask, unsigned int* __restrict__ bits)
{
  const int gid = blockIdx.x * 256 + threadIdx.x;
  unsigned long long bal = __ballot(mask[gid] != 0);
  if ((threadIdx.x & 63) == 0) {
    const int wbase = gid >> 5;
    bits[wbase]     = (unsigned int)bal;
    bits[wbase + 1] = (unsigned int)(bal >> 32);
  }
}

// ---------------------------------------------------------------------------
// LayerNorm: fp32 [8192,768] -> bf16 [8192,768]
// ---------------------------------------------------------------------------
__global__ __launch_bounds__(256) void ln_kernel(
    const float* __restrict__ xin, const float* __restrict__ gamma,
    const float* __restrict__ beta, bf16_t* __restrict__ outb)
{
  __shared__ float red[8];
  const int row = blockIdx.x;
  const float* xr = xin + (size_t)row * 768;
  const int t = threadIdx.x;
  float v0 = xr[t], v1 = xr[t + 256], v2 = xr[t + 512];
  float s  = v0 + v1 + v2;
  float s2 = v0 * v0 + v1 * v1 + v2 * v2;
#pragma unroll
  for (int m = 32; m >= 1; m >>= 1) {
    s  += __shfl_xor(s, m, 64);
    s2 += __shfl_xor(s2, m, 64);
  }
  if ((t & 63) == 0) { red[t >> 6] = s; red[4 + (t >> 6)] = s2; }
  __syncthreads();
  s  = red[0] + red[1] + red[2] + red[3];
  s2 = red[4] + red[5] + red[6] + red[7];
  const float mu  = s * (1.0f / 768.0f);
  const float var = s2 * (1.0f / 768.0f) - mu * mu;
  const float rs  = rsqrtf(var + 1e-5f);
  bf16_t* orow = outb + (size_t)row * 768;
  orow[t]       = (bf16_t)((v0 - mu) * rs * gamma[t]       + beta[t]);
  orow[t + 256] = (bf16_t)((v1 - mu) * rs * gamma[t + 256] + beta[t + 256]);
  orow[t + 512] = (bf16_t)((v2 - mu) * rs * gamma[t + 512] + beta[t + 512]);
}

// ---------------------------------------------------------------------------
// GEMM: C[M,N] = A[M,K] @ Bt[N,K]^T  (128x128 tile, BK=32, 4 waves)
// ---------------------------------------------------------------------------
template <bool RELU, bool OUT_F32, bool HAS_BIAS, bool HAS_RES>
__global__ __launch_bounds__(256) void gemm_kernel(
    const bf16_t* __restrict__ A, const bf16_t* __restrict__ Bt,
    void* __restrict__ Cout, const float* __restrict__ bias,
    const float* __restrict__ res, int Mdim, int Ndim, int Kdim)
{
  __shared__ __align__(16) bf16_t As[128 * 32];
  __shared__ __align__(16) bf16_t Bs[128 * 32];
  const int tid = threadIdx.x;
  const int lane = tid & 63, w = tid >> 6;
  const int l15 = lane & 15, g = lane >> 4;
  const int bm = blockIdx.y * 128, bn = blockIdx.x * 128;
  const int wr = (w >> 1) * 64, wc = (w & 1) * 64;

  f32x4 acc[4][4] = {};
  const int nK = Kdim >> 5;
  for (int kt = 0; kt < nK; ++kt) {
    const int k0 = kt << 5;
#pragma unroll
    for (int it = 0; it < 2; ++it) {
      const int ch = it * 256 + tid;
      const int r = ch >> 2, cc = ch & 3;
      gload16(A  + (size_t)(bm + r) * Kdim + k0 + cc * 8, As + ch * 8);
      gload16(Bt + (size_t)(bn + r) * Kdim + k0 + cc * 8, Bs + ch * 8);
    }
    __syncthreads();
    bf16x8 af[4], bfr[4];
#pragma unroll
    for (int i = 0; i < 4; ++i)
      af[i] = *(const bf16x8*)(As + (wr + i * 16 + l15) * 32 + g * 8);
#pragma unroll
    for (int j = 0; j < 4; ++j)
      bfr[j] = *(const bf16x8*)(Bs + (wc + j * 16 + l15) * 32 + g * 8);
#pragma unroll
    for (int i = 0; i < 4; ++i)
#pragma unroll
      for (int j = 0; j < 4; ++j)
        acc[i][j] = mfma16(af[i], bfr[j], acc[i][j]);
    __syncthreads();
  }

#pragma unroll
  for (int i = 0; i < 4; ++i) {
#pragma unroll
    for (int j = 0; j < 4; ++j) {
      const int col = bn + wc + j * 16 + l15;
#pragma unroll
      for (int r = 0; r < 4; ++r) {
        const int row = bm + wr + i * 16 + g * 4 + r;
        float v = acc[i][j][r];
        if constexpr (HAS_BIAS) v += bias[col];
        if constexpr (HAS_RES)  v += res[(size_t)row * Ndim + col];
        if constexpr (RELU)     v = fmaxf(v, 0.f);
        if constexpr (OUT_F32)
          ((float*)Cout)[(size_t)row * Ndim + col] = v;
        else
          ((bf16_t*)Cout)[(size_t)row * Ndim + col] = (bf16_t)v;
      }
    }
  }
}

// ---------------------------------------------------------------------------
// V transpose: qkv v-columns -> vT[(bh*64+d)][s]
// ---------------------------------------------------------------------------
__global__ __launch_bounds__(256) void transpose_v(
    const bf16_t* __restrict__ qkv, bf16_t* __restrict__ vT)
{
  __shared__ bf16_t t[64][66];
  const int st = blockIdx.x;
  const int bh = blockIdx.y;
  const int b = bh / 12, h = bh % 12;
  const int tid = threadIdx.x;
#pragma unroll
  for (int it = 0; it < 2; ++it) {
    const int ch = it * 256 + tid;
    const int r = ch >> 3, c = ch & 7;
    bf16x8 vv = *(const bf16x8*)(qkv + (size_t)(b * 2048 + st * 64 + r) * 2304 +
                                 1536 + h * 64 + c * 8);
#pragma unroll
    for (int j = 0; j < 8; ++j) t[r][c * 8 + j] = vv[j];
  }
  __syncthreads();
#pragma unroll
  for (int it = 0; it < 2; ++it) {
    const int ch = it * 256 + tid;
    const int d = ch >> 3, c = ch & 7;
    bf16x8 o;
#pragma unroll
    for (int j = 0; j < 8; ++j) o[j] = t[c * 8 + j][d];
    *(bf16x8*)(vT + (size_t)(bh * 64 + d) * 2048 + st * 64 + c * 8) = o;
  }
}

// ---------------------------------------------------------------------------
// Flash attention, 32x32 MFMA form. Block = (bh, qt), 4 waves x 32 q rows.
// Lane (q=lane&31, hi=lane>>5). S^T tile = mfma32(K,Q): lane's 16 regs hold
// k-rows (r&3)+8*(r>>2)+4*hi of one q column. Softmax in-register (1 shuffle).
// P -> PV B-frags purely in-register: pk2 pairs + v_permlane32_swap_b32.
// K/V double-buffered LDS (XOR-swizzled), 1 barrier/kt.
// Q pre-scaled by log2(e)/sqrt(DH); softmax in exp2 domain.
// ---------------------------------------------------------------------------
__global__ __launch_bounds__(256, 2) void attn_kernel(
    const bf16_t* __restrict__ qkv, const bf16_t* __restrict__ vT,
    const unsigned int* __restrict__ mbits, bf16_t* __restrict__ ctx)
{
  __shared__ __align__(16) bf16_t KsBuf[2][128 * 64];   // [s=128][d=64] swizzled
  __shared__ __align__(16) bf16_t VsBuf[2][64 * 128];   // [d=64][s=128] swizzled
  const int tid = threadIdx.x;
  const int lane = tid & 63, w = tid >> 6;
  const int q32 = lane & 31, hi = lane >> 5;
  const int bh = blockIdx.x;      // bh-major => XCD = bh % 8 (K/V L2 affinity)
  const int qt = blockIdx.y;
  const int b = bh / 12, h = bh % 12;
  const int qrow0 = qt * 128 + w * 32;
  const int qabs = qrow0 + q32;

  // Q B-frags: Q[qabs][h*64 + c*16 + hi*8 + e]
  bf16x8 qf[4];
#pragma unroll
  for (int c = 0; c < 4; ++c)
    qf[c] = *(const bf16x8*)(qkv + (size_t)(b * 2048 + qabs) * 2304 +
                             h * 64 + c * 16 + hi * 8);

  auto stage = [&](bf16_t* ks, bf16_t* vs, int kt) {
    const size_t kb = (size_t)(b * 2048 + kt * 128);
#pragma unroll
    for (int it = 0; it < 4; ++it) {
      const int ch = it * 256 + tid;         // K: 128 rows x 8 chunks
      const int r = ch >> 3, c = ch & 7;
      gload16(qkv + (kb + r) * 2304 + 768 + h * 64 + ((c ^ (r & 7)) * 8), ks + ch * 8);
    }
#pragma unroll
    for (int it = 0; it < 4; ++it) {
      const int ch = it * 256 + tid;         // V^T: 64 rows x 16 chunks
      const int r = ch >> 4, c = ch & 15;
      gload16(vT + (size_t)(bh * 64 + r) * 2048 + kt * 128 + ((c ^ (r & 7)) * 8),
              vs + ch * 8);
    }
  };

  f32x16 oacc[2] = {};
  float mrun = NEGF, lrun = 0.f;

  stage(KsBuf[0], VsBuf[0], 0);
  __syncthreads();

  for (int kt = 0; kt < 16; ++kt) {
    const bf16_t* ksc = (kt & 1) ? KsBuf[1] : KsBuf[0];
    const bf16_t* vsc = (kt & 1) ? VsBuf[1] : VsBuf[0];
    if (kt < 15)
      stage((kt & 1) ? KsBuf[0] : KsBuf[1], (kt & 1) ? VsBuf[0] : VsBuf[1], kt + 1);

    const uint4 mm = *(const uint4*)(mbits + (size_t)(b * 2048 + qabs) * 64 + kt * 4);
    const unsigned mwv[4] = {mm.x >> (hi * 4), mm.y >> (hi * 4),
                             mm.z >> (hi * 4), mm.w >> (hi * 4)};

    // ---- S^T = K @ Q^T from LDS: sacc[kb] = 32k x 32q tile ----
    f32x16 sacc[4] = {};
#pragma unroll
    for (int c = 0; c < 4; ++c) {
#pragma unroll
      for (int kb = 0; kb < 4; ++kb) {
        const int row = kb * 32 + q32;
        const int slot = (2 * c + hi) ^ (row & 7);
        bf16x8 kf = *(const bf16x8*)(ksc + row * 64 + slot * 8);
        sacc[kb] = mfma32(kf, qf[c], sacc[kb]);
      }
    }

    // ---- mask + online softmax (exp2 domain), all in-register ----
    float rmax = NEGF;
#pragma unroll
    for (int kb = 0; kb < 4; ++kb) {
#pragma unroll
      for (int rq = 0; rq < 4; ++rq) {
        const unsigned sel = mwv[kb] >> (8 * rq);
#pragma unroll
        for (int i = 0; i < 4; ++i) {
          const float s = ((sel >> i) & 1u) ? NEGF : sacc[kb][rq * 4 + i];
          sacc[kb][rq * 4 + i] = s;
          rmax = fmaxf(rmax, s);
        }
      }
    }
    rmax = fmaxf(rmax, __shfl_xor(rmax, 32, 64));
    const float mn = fmaxf(mrun, rmax);
    const float sc = exp2_fast(mrun - mn);
    float ps = 0.f;
#pragma unroll
    for (int kb = 0; kb < 4; ++kb)
#pragma unroll
      for (int i = 0; i < 16; ++i) {
        const float p = exp2_fast(sacc[kb][i] - mn);   // exp2(-1e30-mn)=0
        sacc[kb][i] = p;
        ps += p;
      }
    ps += __shfl_xor(ps, 32, 64);
    mrun = mn;
    lrun = lrun * sc + ps;
    oacc[0] *= sc;
    oacc[1] *= sc;

    // ---- PV: O^T[d][q] += V^T @ P, P frags built via permlane32_swap ----
#pragma unroll
    for (int kb = 0; kb < 4; ++kb) {
      unsigned u0 = pk2(sacc[kb][0],  sacc[kb][1]);
      unsigned u1 = pk2(sacc[kb][2],  sacc[kb][3]);
      unsigned u2 = pk2(sacc[kb][4],  sacc[kb][5]);
      unsigned u3 = pk2(sacc[kb][6],  sacc[kb][7]);
      unsigned u4 = pk2(sacc[kb][8],  sacc[kb][9]);
      unsigned u5 = pk2(sacc[kb][10], sacc[kb][11]);
      unsigned u6 = pk2(sacc[kb][12], sacc[kb][13]);
      unsigned u7 = pk2(sacc[kb][14], sacc[kb][15]);
      pl32_swap(u0, u2);  pl32_swap(u1, u3);   // ks=0: words (u0,u1,u2,u3)
      pl32_swap(u4, u6);  pl32_swap(u5, u7);   // ks=1: words (u4,u5,u6,u7)
      bf16x8 p0 = frag4(u0, u1, u2, u3);
      bf16x8 p1 = frag4(u4, u5, u6, u7);
#pragma unroll
      for (int ks = 0; ks < 2; ++ks) {
        const bf16x8 pf = ks ? p1 : p0;
        const int cg = kb * 4 + ks * 2 + hi;
#pragma unroll
        for (int dt = 0; dt < 2; ++dt) {
          const int row = dt * 32 + q32;
          bf16x8 vf = *(const bf16x8*)(vsc + row * 128 + ((cg ^ (row & 7)) * 8));
          oacc[dt] = mfma32(vf, pf, oacc[dt]);
        }
      }
    }
    __syncthreads();
  }

  // ---- normalize + write: lane holds O^T[d=dt*32+(r&3)+8*(r>>2)+4hi][qabs] ----
  const float inv = (lrun > 0.f) ? 1.f / lrun : 0.f;
  bf16_t* crow = ctx + (size_t)(b * 2048 + qabs) * 768 + h * 64;
#pragma unroll
  for (int dt = 0; dt < 2; ++dt)
#pragma unroll
    for (int rq = 0; rq < 4; ++rq) {
      bf16x4 ov = {(bf16_t)(oacc[dt][rq * 4 + 0] * inv),
                   (bf16_t)(oacc[dt][rq * 4 + 1] * inv),
                   (bf16_t)(oacc[dt][rq * 4 + 2] * inv),
                   (bf16_t)(oacc[dt][rq * 4 + 3] * inv)};
      *(bf16x4*)(crow + dt * 32 + rq * 8 + hi * 4) = ov;
    }
}

// ---------------------------------------------------------------------------
// Host launcher
// ---------------------------------------------------------------------------
extern "C" void kernel_launch(void* const* d_in, const int* in_sizes, int n_in,
                              void* d_out, int out_size, void* d_ws, size_t ws_size,
                              hipStream_t stream) {
  const float* x  = (const float*)d_in[0];
  const int* mask = (const int*)d_in[1];
  const float* wq = (const float*)d_in[2];
  const float* wk = (const float*)d_in[3];
  const float* wv = (const float*)d_in[4];
  const float* wo = (const float*)d_in[5];
  const float* bo = (const float*)d_in[6];
  const float* w1 = (const float*)d_in[7];
  const float* w2 = (const float*)d_in[8];
  const float* g1 = (const float*)d_in[9];
  const float* b1 = (const float*)d_in[10];
  const float* g2 = (const float*)d_in[11];
  const float* b2 = (const float*)d_in[12];
  float* out = (float*)d_out;

  char* p = (char*)d_ws;
  bf16_t* WQKVT = (bf16_t*)p; p += (size_t)2304 * 768 * 2;
  bf16_t* WOT   = (bf16_t*)p; p += (size_t)768 * 768 * 2;
  bf16_t* W1T   = (bf16_t*)p; p += (size_t)3072 * 768 * 2;
  bf16_t* W2T   = (bf16_t*)p; p += (size_t)768 * 3072 * 2;
  unsigned int* MB = (unsigned int*)p; p += (size_t)4 * 2048 * 64 * 4;
  bf16_t* Hbuf  = (bf16_t*)p; p += (size_t)8192 * 768 * 2;
  float*  X2    = (float*)p;  p += (size_t)8192 * 768 * 4;
  bf16_t* QKV   = (bf16_t*)p; p += (size_t)8192 * 2304 * 2;
  bf16_t* CTX   = (bf16_t*)p;
  bf16_t* FFN   = QKV;
  bf16_t* VT    = Hbuf;

  const dim3 tb(32, 8);
  // wq carries 1/sqrt(DH) * log2(e) so softmax runs in exp2 domain
  transpose_conv<<<dim3(24, 24), tb, 0, stream>>>(wq, WQKVT,              768, 768, 0.125f * LOG2E);
  transpose_conv<<<dim3(24, 24), tb, 0, stream>>>(wk, WQKVT + 768 * 768,  768, 768, 1.f);
  transpose_conv<<<dim3(24, 24), tb, 0, stream>>>(wv, WQKVT + 1536 * 768, 768, 768, 1.f);
  transpose_conv<<<dim3(24, 24), tb, 0, stream>>>(wo, WOT, 768, 768, 1.f);
  transpose_conv<<<dim3(96, 24), tb, 0, stream>>>(w1, W1T, 768, 3072, 1.f);
  transpose_conv<<<dim3(24, 96), tb, 0, stream>>>(w2, W2T, 3072, 768, 1.f);
  pack_mask<<<65536, 256, 0, stream>>>(mask, MB);

  ln_kernel<<<8192, 256, 0, stream>>>(x, g1, b1, Hbuf);
  gemm_kernel<false, false, false, false><<<dim3(18, 64), 256, 0, stream>>>(
      Hbuf, WQKVT, QKV, nullptr, nullptr, 8192, 2304, 768);
  transpose_v<<<dim3(32, 48), 256, 0, stream>>>(QKV, VT);
  attn_kernel<<<dim3(48, 16), 256, 0, stream>>>(QKV, VT, MB, CTX);
  gemm_kernel<false, true, true, true><<<dim3(6, 64), 256, 0, stream>>>(
      CTX, WOT, X2, bo, x, 8192, 768, 768);

  ln_kernel<<<8192, 256, 0, stream>>>(X2, g2, b2, Hbuf);
  gemm_kernel<true, false, false, false><<<dim3(24, 64), 256, 0, stream>>>(
      Hbuf, W1T, FFN, nullptr, nullptr, 8192, 3072, 768);
  gemm_kernel<false, true, false, true><<<dim3(6, 64), 256, 0, stream>>>(
      FFN, W2T, out, nullptr, X2, 8192, 768, 3072);
}

// Round 6
// 319.558 us; speedup vs baseline: 1.7916x; 1.1463x over previous
//
#include <hip/hip_runtime.h>
#include <cstdint>

// ---------------------------------------------------------------------------
// EncoderLayer (B=4, S=2048, D=768, H=12, FF=3072) on MI355X / gfx950.
// bf16 MFMA everywhere. GEMM: 128x128 tile, BK=64, XOR-swizzled LDS,
// XCD-chunked block swizzle, vectorized epilogue via LDS bounce.
// Attention: 32x32x16 MFMA, swapped QK^T, in-register softmax, permlane P.
// ---------------------------------------------------------------------------

typedef __bf16 bf16_t;
typedef __bf16 bf16x8 __attribute__((ext_vector_type(8)));
typedef __bf16 bf16x4 __attribute__((ext_vector_type(4)));
typedef __bf16 bf16x2 __attribute__((ext_vector_type(2)));
typedef float  f32x4  __attribute__((ext_vector_type(4)));
typedef float  f32x16 __attribute__((ext_vector_type(16)));

#define NEGF (-1e30f)
#define LOG2E 1.44269504088896340736f

__device__ __forceinline__ float exp2_fast(float x) {
  float r;
  asm("v_exp_f32 %0, %1" : "=v"(r) : "v"(x));
  return r;
}

__device__ __forceinline__ f32x4 mfma16(bf16x8 a, bf16x8 b, f32x4 c) {
  return __builtin_amdgcn_mfma_f32_16x16x32_bf16(a, b, c, 0, 0, 0);
}
__device__ __forceinline__ f32x16 mfma32(bf16x8 a, bf16x8 b, f32x16 c) {
  return __builtin_amdgcn_mfma_f32_32x32x16_bf16(a, b, c, 0, 0, 0);
}

__device__ __forceinline__ void gload16(const bf16_t* gsrc, bf16_t* lds) {
  __builtin_amdgcn_global_load_lds(
      (const __attribute__((address_space(1))) unsigned int*)(uintptr_t)gsrc,
      (__attribute__((address_space(3))) unsigned int*)(uintptr_t)lds,
      16, 0, 0);
}

__device__ __forceinline__ unsigned pk2(float a, float b) {
  bf16x2 v = {(bf16_t)a, (bf16_t)b};
  return __builtin_bit_cast(unsigned, v);
}
__device__ __forceinline__ void pl32_swap(unsigned& a, unsigned& b) {
  asm("v_permlane32_swap_b32 %0, %1" : "+v"(a), "+v"(b));
}
__device__ __forceinline__ bf16x8 frag4(unsigned w0, unsigned w1,
                                        unsigned w2, unsigned w3) {
  union { unsigned u[4]; bf16x8 v; } t;
  t.u[0] = w0; t.u[1] = w1; t.u[2] = w2; t.u[3] = w3;
  return t.v;
}

// ---------------------------------------------------------------------------
// Weight prep: Wt[n*K+k] = W[k*N+n] * scale, fp32 -> bf16
// ---------------------------------------------------------------------------
__global__ __launch_bounds__(256) void transpose_conv(
    const float* __restrict__ W, bf16_t* __restrict__ Wt, int K, int N, float scale)
{
  __shared__ float tile[32][33];
  const int n0 = blockIdx.x * 32, k0 = blockIdx.y * 32;
  const int tx = threadIdx.x, ty = threadIdx.y;
#pragma unroll
  for (int i = 0; i < 32; i += 8)
    tile[ty + i][tx] = W[(size_t)(k0 + ty + i) * N + n0 + tx];
  __syncthreads();
#pragma unroll
  for (int i = 0; i < 32; i += 8)
    Wt[(size_t)(n0 + ty + i) * K + k0 + tx] = (bf16_t)(tile[tx][ty + i] * scale);
}

// ---------------------------------------------------------------------------
// Mask pack: int32 [B,S,S] -> bits [B,S,S/32] (bit=1 means masked)
// ---------------------------------------------------------------------------
__global__ __launch_bounds__(256) void pack_mask(
    const int* __restrict__ mask, unsigned int* __restrict__ bits)
{
  const int gid = blockIdx.x * 256 + threadIdx.x;
  unsigned long long bal = __ballot(mask[gid] != 0);
  if ((threadIdx.x & 63) == 0) {
    const int wbase = gid >> 5;
    bits[wbase]     = (unsigned int)bal;
    bits[wbase + 1] = (unsigned int)(bal >> 32);
  }
}

// ---------------------------------------------------------------------------
// LayerNorm: fp32 [8192,768] -> bf16 [8192,768]
// ---------------------------------------------------------------------------
__global__ __launch_bounds__(256) void ln_kernel(
    const float* __restrict__ xin, const float* __restrict__ gamma,
    const float* __restrict__ beta, bf16_t* __restrict__ outb)
{
  __shared__ float red[8];
  const int row = blockIdx.x;
  const float* xr = xin + (size_t)row * 768;
  const int t = threadIdx.x;
  float v0 = xr[t], v1 = xr[t + 256], v2 = xr[t + 512];
  float s  = v0 + v1 + v2;
  float s2 = v0 * v0 + v1 * v1 + v2 * v2;
#pragma unroll
  for (int m = 32; m >= 1; m >>= 1) {
    s  += __shfl_xor(s, m, 64);
    s2 += __shfl_xor(s2, m, 64);
  }
  if ((t & 63) == 0) { red[t >> 6] = s; red[4 + (t >> 6)] = s2; }
  __syncthreads();
  s  = red[0] + red[1] + red[2] + red[3];
  s2 = red[4] + red[5] + red[6] + red[7];
  const float mu  = s * (1.0f / 768.0f);
  const float var = s2 * (1.0f / 768.0f) - mu * mu;
  const float rs  = rsqrtf(var + 1e-5f);
  bf16_t* orow = outb + (size_t)row * 768;
  orow[t]       = (bf16_t)((v0 - mu) * rs * gamma[t]       + beta[t]);
  orow[t + 256] = (bf16_t)((v1 - mu) * rs * gamma[t + 256] + beta[t + 256]);
  orow[t + 512] = (bf16_t)((v2 - mu) * rs * gamma[t + 512] + beta[t + 512]);
}

// ---------------------------------------------------------------------------
// GEMM: C[M,N] = A[M,K] @ Bt[N,K]^T. 128x128 tile, BK=64, 4 waves (64x64).
// XOR-swizzled LDS (128B rows), XCD-chunked block swizzle, LDS-bounce epilogue.
// ---------------------------------------------------------------------------
template <bool RELU, bool OUT_F32, bool HAS_BIAS, bool HAS_RES>
__global__ __launch_bounds__(256) void gemm_kernel(
    const bf16_t* __restrict__ A, const bf16_t* __restrict__ Bt,
    void* __restrict__ Cout, const float* __restrict__ bias,
    const float* __restrict__ res, int Mdim, int Ndim, int Kdim)
{
  __shared__ __align__(16) bf16_t Smem[2][128 * 64];
  bf16_t* const As = Smem[0];
  bf16_t* const Bs = Smem[1];
  const int tid = threadIdx.x;
  const int lane = tid & 63, w = tid >> 6;
  const int l15 = lane & 15, g = lane >> 4;
  // XCD-chunked swizzle: hw position p -> work id wg; XCD p%8 owns a
  // contiguous work range (all grids here have nwg % 8 == 0 -> bijective).
  const int gx = gridDim.x;
  const int nwg = gx * gridDim.y;
  const int p = blockIdx.y * gx + blockIdx.x;
  const int wg = (p & 7) * (nwg >> 3) + (p >> 3);
  const int bm = (wg / gx) * 128, bn = (wg % gx) * 128;
  const int wr = (w >> 1) * 64, wc = (w & 1) * 64;
  const int swz = l15 & 7;

  f32x4 acc[4][4] = {};
  const int nK = Kdim >> 6;
  for (int kt = 0; kt < nK; ++kt) {
    const int k0 = kt << 6;
#pragma unroll
    for (int it = 0; it < 4; ++it) {
      const int ch = it * 256 + tid;        // 0..1023: row r, 16B chunk c
      const int r = ch >> 3, c = ch & 7;
      gload16(A + (size_t)(bm + r) * Kdim + k0 + ((c ^ (r & 7)) * 8), As + ch * 8);
    }
#pragma unroll
    for (int it = 0; it < 4; ++it) {
      const int ch = it * 256 + tid;
      const int r = ch >> 3, c = ch & 7;
      gload16(Bt + (size_t)(bn + r) * Kdim + k0 + ((c ^ (r & 7)) * 8), Bs + ch * 8);
    }
    __syncthreads();
#pragma unroll
    for (int kk = 0; kk < 2; ++kk) {
      bf16x8 af[4], bfr[4];
#pragma unroll
      for (int i = 0; i < 4; ++i)
        af[i] = *(const bf16x8*)(As + (wr + i * 16 + l15) * 64 +
                                 (((kk * 4 + g) ^ swz) * 8));
#pragma unroll
      for (int j = 0; j < 4; ++j)
        bfr[j] = *(const bf16x8*)(Bs + (wc + j * 16 + l15) * 64 +
                                  (((kk * 4 + g) ^ swz) * 8));
#pragma unroll
      for (int i = 0; i < 4; ++i)
#pragma unroll
        for (int j = 0; j < 4; ++j)
          acc[i][j] = mfma16(af[i], bfr[j], acc[i][j]);
    }
    __syncthreads();
  }

  // ---- epilogue: LDS bounce (wave-private 8KB) -> vectorized stores ----
  if constexpr (!OUT_F32) {
    bf16_t* const wb = &Smem[0][0] + w * 4096;   // bf16[64][64], chunk-swizzled
#pragma unroll
    for (int i = 0; i < 4; ++i)
#pragma unroll
      for (int j = 0; j < 4; ++j)
#pragma unroll
        for (int r = 0; r < 4; ++r) {
          const int row = i * 16 + g * 4 + r, col = j * 16 + l15;
          float v = acc[i][j][r];
          if constexpr (RELU) v = fmaxf(v, 0.f);
          *(bf16_t*)((char*)wb + row * 128 + ((col * 2) ^ ((row & 7) << 4))) =
              (bf16_t)v;
        }
    __syncthreads();
    bf16_t* const crow0 = (bf16_t*)Cout + (size_t)(bm + wr) * Ndim + bn + wc;
    const int c = lane & 7;
#pragma unroll
    for (int ps = 0; ps < 8; ++ps) {
      const int row = (lane >> 3) + ps * 8;
      bf16x8 v = *(const bf16x8*)((char*)wb + row * 128 +
                                  ((c * 16) ^ ((row & 7) << 4)));
      *(bf16x8*)(crow0 + (size_t)row * Ndim + c * 8) = v;
    }
  } else {
    float* const fb = (float*)&Smem[0][0] + w * 2048;  // f32[64][32], swizzled
    const int c = lane & 7;
#pragma unroll
    for (int jh = 0; jh < 2; ++jh) {
      if (jh) __syncthreads();
#pragma unroll
      for (int i = 0; i < 4; ++i)
#pragma unroll
        for (int jj = 0; jj < 2; ++jj)
#pragma unroll
          for (int r = 0; r < 4; ++r) {
            const int row = i * 16 + g * 4 + r, col = jj * 16 + l15;
            *(float*)((char*)fb + row * 128 + ((col * 4) ^ ((row & 7) << 4))) =
                acc[i][jh * 2 + jj][r];
          }
      __syncthreads();
      const int gcol = bn + wc + jh * 32 + c * 4;
      float4 bv = {0.f, 0.f, 0.f, 0.f};
      if constexpr (HAS_BIAS) bv = *(const float4*)(bias + gcol);
#pragma unroll
      for (int ps = 0; ps < 8; ++ps) {
        const int row = (lane >> 3) + ps * 8;
        float4 v = *(const float4*)((char*)fb + row * 128 +
                                    ((c * 16) ^ ((row & 7) << 4)));
        if constexpr (HAS_BIAS) { v.x += bv.x; v.y += bv.y; v.z += bv.z; v.w += bv.w; }
        if constexpr (HAS_RES) {
          const float4 rv = *(const float4*)(res + (size_t)(bm + wr + row) * Ndim + gcol);
          v.x += rv.x; v.y += rv.y; v.z += rv.z; v.w += rv.w;
        }
        *(float4*)((float*)Cout + (size_t)(bm + wr + row) * Ndim + gcol) = v;
      }
    }
  }
}

// ---------------------------------------------------------------------------
// V transpose: qkv v-columns -> vT[(bh*64+d)][s]
// ---------------------------------------------------------------------------
__global__ __launch_bounds__(256) void transpose_v(
    const bf16_t* __restrict__ qkv, bf16_t* __restrict__ vT)
{
  __shared__ bf16_t t[64][66];
  const int st = blockIdx.x;
  const int bh = blockIdx.y;
  const int b = bh / 12, h = bh % 12;
  const int tid = threadIdx.x;
#pragma unroll
  for (int it = 0; it < 2; ++it) {
    const int ch = it * 256 + tid;
    const int r = ch >> 3, c = ch & 7;
    bf16x8 vv = *(const bf16x8*)(qkv + (size_t)(b * 2048 + st * 64 + r) * 2304 +
                                 1536 + h * 64 + c * 8);
#pragma unroll
    for (int j = 0; j < 8; ++j) t[r][c * 8 + j] = vv[j];
  }
  __syncthreads();
#pragma unroll
  for (int it = 0; it < 2; ++it) {
    const int ch = it * 256 + tid;
    const int d = ch >> 3, c = ch & 7;
    bf16x8 o;
#pragma unroll
    for (int j = 0; j < 8; ++j) o[j] = t[c * 8 + j][d];
    *(bf16x8*)(vT + (size_t)(bh * 64 + d) * 2048 + st * 64 + c * 8) = o;
  }
}

// ---------------------------------------------------------------------------
// Flash attention, 32x32 MFMA form. Block = (bh, qt), 4 waves x 32 q rows.
// ---------------------------------------------------------------------------
__global__ __launch_bounds__(256, 2) void attn_kernel(
    const bf16_t* __restrict__ qkv, const bf16_t* __restrict__ vT,
    const unsigned int* __restrict__ mbits, bf16_t* __restrict__ ctx)
{
  __shared__ __align__(16) bf16_t KsBuf[2][128 * 64];   // [s=128][d=64] swizzled
  __shared__ __align__(16) bf16_t VsBuf[2][64 * 128];   // [d=64][s=128] swizzled
  const int tid = threadIdx.x;
  const int lane = tid & 63, w = tid >> 6;
  const int q32 = lane & 31, hi = lane >> 5;
  const int bh = blockIdx.x;      // bh-major => XCD = bh % 8 (K/V L2 affinity)
  const int qt = blockIdx.y;
  const int b = bh / 12, h = bh % 12;
  const int qrow0 = qt * 128 + w * 32;
  const int qabs = qrow0 + q32;

  bf16x8 qf[4];
#pragma unroll
  for (int c = 0; c < 4; ++c)
    qf[c] = *(const bf16x8*)(qkv + (size_t)(b * 2048 + qabs) * 2304 +
                             h * 64 + c * 16 + hi * 8);

  auto stage = [&](bf16_t* ks, bf16_t* vs, int kt) {
    const size_t kb = (size_t)(b * 2048 + kt * 128);
#pragma unroll
    for (int it = 0; it < 4; ++it) {
      const int ch = it * 256 + tid;
      const int r = ch >> 3, c = ch & 7;
      gload16(qkv + (kb + r) * 2304 + 768 + h * 64 + ((c ^ (r & 7)) * 8), ks + ch * 8);
    }
#pragma unroll
    for (int it = 0; it < 4; ++it) {
      const int ch = it * 256 + tid;
      const int r = ch >> 4, c = ch & 15;
      gload16(vT + (size_t)(bh * 64 + r) * 2048 + kt * 128 + ((c ^ (r & 7)) * 8),
              vs + ch * 8);
    }
  };

  f32x16 oacc[2] = {};
  float mrun = NEGF, lrun = 0.f;

  stage(KsBuf[0], VsBuf[0], 0);
  __syncthreads();

  for (int kt = 0; kt < 16; ++kt) {
    const bf16_t* ksc = (kt & 1) ? KsBuf[1] : KsBuf[0];
    const bf16_t* vsc = (kt & 1) ? VsBuf[1] : VsBuf[0];
    if (kt < 15)
      stage((kt & 1) ? KsBuf[0] : KsBuf[1], (kt & 1) ? VsBuf[0] : VsBuf[1], kt + 1);

    const uint4 mm = *(const uint4*)(mbits + (size_t)(b * 2048 + qabs) * 64 + kt * 4);
    const unsigned mwv[4] = {mm.x >> (hi * 4), mm.y >> (hi * 4),
                             mm.z >> (hi * 4), mm.w >> (hi * 4)};

    f32x16 sacc[4] = {};
#pragma unroll
    for (int c = 0; c < 4; ++c) {
#pragma unroll
      for (int kb = 0; kb < 4; ++kb) {
        const int row = kb * 32 + q32;
        const int slot = (2 * c + hi) ^ (row & 7);
        bf16x8 kf = *(const bf16x8*)(ksc + row * 64 + slot * 8);
        sacc[kb] = mfma32(kf, qf[c], sacc[kb]);
      }
    }

    float rmax = NEGF;
#pragma unroll
    for (int kb = 0; kb < 4; ++kb) {
#pragma unroll
      for (int rq = 0; rq < 4; ++rq) {
        const unsigned sel = mwv[kb] >> (8 * rq);
#pragma unroll
        for (int i = 0; i < 4; ++i) {
          const float s = ((sel >> i) & 1u) ? NEGF : sacc[kb][rq * 4 + i];
          sacc[kb][rq * 4 + i] = s;
          rmax = fmaxf(rmax, s);
        }
      }
    }
    rmax = fmaxf(rmax, __shfl_xor(rmax, 32, 64));
    const float mn = fmaxf(mrun, rmax);
    const float sc = exp2_fast(mrun - mn);
    float ps = 0.f;
#pragma unroll
    for (int kb = 0; kb < 4; ++kb)
#pragma unroll
      for (int i = 0; i < 16; ++i) {
        const float p = exp2_fast(sacc[kb][i] - mn);
        sacc[kb][i] = p;
        ps += p;
      }
    ps += __shfl_xor(ps, 32, 64);
    mrun = mn;
    lrun = lrun * sc + ps;
    oacc[0] *= sc;
    oacc[1] *= sc;

#pragma unroll
    for (int kb = 0; kb < 4; ++kb) {
      unsigned u0 = pk2(sacc[kb][0],  sacc[kb][1]);
      unsigned u1 = pk2(sacc[kb][2],  sacc[kb][3]);
      unsigned u2 = pk2(sacc[kb][4],  sacc[kb][5]);
      unsigned u3 = pk2(sacc[kb][6],  sacc[kb][7]);
      unsigned u4 = pk2(sacc[kb][8],  sacc[kb][9]);
      unsigned u5 = pk2(sacc[kb][10], sacc[kb][11]);
      unsigned u6 = pk2(sacc[kb][12], sacc[kb][13]);
      unsigned u7 = pk2(sacc[kb][14], sacc[kb][15]);
      pl32_swap(u0, u2);  pl32_swap(u1, u3);
      pl32_swap(u4, u6);  pl32_swap(u5, u7);
      bf16x8 p0 = frag4(u0, u1, u2, u3);
      bf16x8 p1 = frag4(u4, u5, u6, u7);
#pragma unroll
      for (int ks = 0; ks < 2; ++ks) {
        const bf16x8 pf = ks ? p1 : p0;
        const int cg = kb * 4 + ks * 2 + hi;
#pragma unroll
        for (int dt = 0; dt < 2; ++dt) {
          const int row = dt * 32 + q32;
          bf16x8 vf = *(const bf16x8*)(vsc + row * 128 + ((cg ^ (row & 7)) * 8));
          oacc[dt] = mfma32(vf, pf, oacc[dt]);
        }
      }
    }
    __syncthreads();
  }

  const float inv = (lrun > 0.f) ? 1.f / lrun : 0.f;
  bf16_t* crow = ctx + (size_t)(b * 2048 + qabs) * 768 + h * 64;
#pragma unroll
  for (int dt = 0; dt < 2; ++dt)
#pragma unroll
    for (int rq = 0; rq < 4; ++rq) {
      bf16x4 ov = {(bf16_t)(oacc[dt][rq * 4 + 0] * inv),
                   (bf16_t)(oacc[dt][rq * 4 + 1] * inv),
                   (bf16_t)(oacc[dt][rq * 4 + 2] * inv),
                   (bf16_t)(oacc[dt][rq * 4 + 3] * inv)};
      *(bf16x4*)(crow + dt * 32 + rq * 8 + hi * 4) = ov;
    }
}

// ---------------------------------------------------------------------------
// Host launcher
// ---------------------------------------------------------------------------
extern "C" void kernel_launch(void* const* d_in, const int* in_sizes, int n_in,
                              void* d_out, int out_size, void* d_ws, size_t ws_size,
                              hipStream_t stream) {
  const float* x  = (const float*)d_in[0];
  const int* mask = (const int*)d_in[1];
  const float* wq = (const float*)d_in[2];
  const float* wk = (const float*)d_in[3];
  const float* wv = (const float*)d_in[4];
  const float* wo = (const float*)d_in[5];
  const float* bo = (const float*)d_in[6];
  const float* w1 = (const float*)d_in[7];
  const float* w2 = (const float*)d_in[8];
  const float* g1 = (const float*)d_in[9];
  const float* b1 = (const float*)d_in[10];
  const float* g2 = (const float*)d_in[11];
  const float* b2 = (const float*)d_in[12];
  float* out = (float*)d_out;

  char* p = (char*)d_ws;
  bf16_t* WQKVT = (bf16_t*)p; p += (size_t)2304 * 768 * 2;
  bf16_t* WOT   = (bf16_t*)p; p += (size_t)768 * 768 * 2;
  bf16_t* W1T   = (bf16_t*)p; p += (size_t)3072 * 768 * 2;
  bf16_t* W2T   = (bf16_t*)p; p += (size_t)768 * 3072 * 2;
  unsigned int* MB = (unsigned int*)p; p += (size_t)4 * 2048 * 64 * 4;
  bf16_t* Hbuf  = (bf16_t*)p; p += (size_t)8192 * 768 * 2;
  float*  X2    = (float*)p;  p += (size_t)8192 * 768 * 4;
  bf16_t* QKV   = (bf16_t*)p; p += (size_t)8192 * 2304 * 2;
  bf16_t* CTX   = (bf16_t*)p;
  bf16_t* FFN   = QKV;
  bf16_t* VT    = Hbuf;

  const dim3 tb(32, 8);
  // wq carries 1/sqrt(DH) * log2(e) so softmax runs in exp2 domain
  transpose_conv<<<dim3(24, 24), tb, 0, stream>>>(wq, WQKVT,              768, 768, 0.125f * LOG2E);
  transpose_conv<<<dim3(24, 24), tb, 0, stream>>>(wk, WQKVT + 768 * 768,  768, 768, 1.f);
  transpose_conv<<<dim3(24, 24), tb, 0, stream>>>(wv, WQKVT + 1536 * 768, 768, 768, 1.f);
  transpose_conv<<<dim3(24, 24), tb, 0, stream>>>(wo, WOT, 768, 768, 1.f);
  transpose_conv<<<dim3(96, 24), tb, 0, stream>>>(w1, W1T, 768, 3072, 1.f);
  transpose_conv<<<dim3(24, 96), tb, 0, stream>>>(w2, W2T, 3072, 768, 1.f);
  pack_mask<<<65536, 256, 0, stream>>>(mask, MB);

  ln_kernel<<<8192, 256, 0, stream>>>(x, g1, b1, Hbuf);
  gemm_kernel<false, false, false, false><<<dim3(18, 64), 256, 0, stream>>>(
      Hbuf, WQKVT, QKV, nullptr, nullptr, 8192, 2304, 768);
  transpose_v<<<dim3(32, 48), 256, 0, stream>>>(QKV, VT);
  attn_kernel<<<dim3(48, 16), 256, 0, stream>>>(QKV, VT, MB, CTX);
  gemm_kernel<false, true, true, true><<<dim3(6, 64), 256, 0, stream>>>(
      CTX, WOT, X2, bo, x, 8192, 768, 768);

  ln_kernel<<<8192, 256, 0, stream>>>(X2, g2, b2, Hbuf);
  gemm_kernel<true, false, false, false><<<dim3(24, 64), 256, 0, stream>>>(
      Hbuf, W1T, FFN, nullptr, nullptr, 8192, 3072, 768);
  gemm_kernel<false, true, false, true><<<dim3(6, 64), 256, 0, stream>>>(
      FFN, W2T, out, nullptr, X2, 8192, 768, 3072);
}

// Round 7
// 316.094 us; speedup vs baseline: 1.8112x; 1.0110x over previous
//
#include <hip/hip_runtime.h>
#include <cstdint>

// ---------------------------------------------------------------------------
// EncoderLayer (B=4, S=2048, D=768, H=12, FF=3072) on MI355X / gfx950.
// bf16 MFMA everywhere. GEMM: 128x128 tile, BK=64, XOR-swizzled LDS,
// XCD-chunked block swizzle, vectorized epilogue via LDS bounce.
// Attention: 32x32x16 MFMA, KVBLK=64 (32KB LDS, 4-5 blocks/CU), swapped QK^T,
// in-register softmax (mask-after-exp, defer-max), permlane P fragments.
// ---------------------------------------------------------------------------

typedef __bf16 bf16_t;
typedef __bf16 bf16x8 __attribute__((ext_vector_type(8)));
typedef __bf16 bf16x4 __attribute__((ext_vector_type(4)));
typedef __bf16 bf16x2 __attribute__((ext_vector_type(2)));
typedef float  f32x4  __attribute__((ext_vector_type(4)));
typedef float  f32x16 __attribute__((ext_vector_type(16)));

#define NEGF (-1e30f)
#define LOG2E 1.44269504088896340736f

__device__ __forceinline__ float exp2_fast(float x) {
  float r;
  asm("v_exp_f32 %0, %1" : "=v"(r) : "v"(x));
  return r;
}

__device__ __forceinline__ f32x4 mfma16(bf16x8 a, bf16x8 b, f32x4 c) {
  return __builtin_amdgcn_mfma_f32_16x16x32_bf16(a, b, c, 0, 0, 0);
}
__device__ __forceinline__ f32x16 mfma32(bf16x8 a, bf16x8 b, f32x16 c) {
  return __builtin_amdgcn_mfma_f32_32x32x16_bf16(a, b, c, 0, 0, 0);
}

__device__ __forceinline__ void gload16(const bf16_t* gsrc, bf16_t* lds) {
  __builtin_amdgcn_global_load_lds(
      (const __attribute__((address_space(1))) unsigned int*)(uintptr_t)gsrc,
      (__attribute__((address_space(3))) unsigned int*)(uintptr_t)lds,
      16, 0, 0);
}

__device__ __forceinline__ unsigned pk2(float a, float b) {
  bf16x2 v = {(bf16_t)a, (bf16_t)b};
  return __builtin_bit_cast(unsigned, v);
}
__device__ __forceinline__ void pl32_swap(unsigned& a, unsigned& b) {
  asm("v_permlane32_swap_b32 %0, %1" : "+v"(a), "+v"(b));
}
__device__ __forceinline__ bf16x8 frag4(unsigned w0, unsigned w1,
                                        unsigned w2, unsigned w3) {
  union { unsigned u[4]; bf16x8 v; } t;
  t.u[0] = w0; t.u[1] = w1; t.u[2] = w2; t.u[3] = w3;
  return t.v;
}

// ---------------------------------------------------------------------------
// Weight prep: Wt[n*K+k] = W[k*N+n] * scale, fp32 -> bf16
// ---------------------------------------------------------------------------
__global__ __launch_bounds__(256) void transpose_conv(
    const float* __restrict__ W, bf16_t* __restrict__ Wt, int K, int N, float scale)
{
  __shared__ float tile[32][33];
  const int n0 = blockIdx.x * 32, k0 = blockIdx.y * 32;
  const int tx = threadIdx.x, ty = threadIdx.y;
#pragma unroll
  for (int i = 0; i < 32; i += 8)
    tile[ty + i][tx] = W[(size_t)(k0 + ty + i) * N + n0 + tx];
  __syncthreads();
#pragma unroll
  for (int i = 0; i < 32; i += 8)
    Wt[(size_t)(n0 + ty + i) * K + k0 + tx] = (bf16_t)(tile[tx][ty + i] * scale);
}

// ---------------------------------------------------------------------------
// Mask pack: int32 [B,S,S] -> bits [B,S,S/32] (bit=1 means masked)
// ---------------------------------------------------------------------------
__global__ __launch_bounds__(256) void pack_mask(
    const int* __restrict__ mask, unsigned int* __restrict__ bits)
{
  const int gid = blockIdx.x * 256 + threadIdx.x;
  unsigned long long bal = __ballot(mask[gid] != 0);
  if ((threadIdx.x & 63) == 0) {
    const int wbase = gid >> 5;
    bits[wbase]     = (unsigned int)bal;
    bits[wbase + 1] = (unsigned int)(bal >> 32);
  }
}

// ---------------------------------------------------------------------------
// LayerNorm: fp32 [8192,768] -> bf16 [8192,768]
// ---------------------------------------------------------------------------
__global__ __launch_bounds__(256) void ln_kernel(
    const float* __restrict__ xin, const float* __restrict__ gamma,
    const float* __restrict__ beta, bf16_t* __restrict__ outb)
{
  __shared__ float red[8];
  const int row = blockIdx.x;
  const float* xr = xin + (size_t)row * 768;
  const int t = threadIdx.x;
  float v0 = xr[t], v1 = xr[t + 256], v2 = xr[t + 512];
  float s  = v0 + v1 + v2;
  float s2 = v0 * v0 + v1 * v1 + v2 * v2;
#pragma unroll
  for (int m = 32; m >= 1; m >>= 1) {
    s  += __shfl_xor(s, m, 64);
    s2 += __shfl_xor(s2, m, 64);
  }
  if ((t & 63) == 0) { red[t >> 6] = s; red[4 + (t >> 6)] = s2; }
  __syncthreads();
  s  = red[0] + red[1] + red[2] + red[3];
  s2 = red[4] + red[5] + red[6] + red[7];
  const float mu  = s * (1.0f / 768.0f);
  const float var = s2 * (1.0f / 768.0f) - mu * mu;
  const float rs  = rsqrtf(var + 1e-5f);
  bf16_t* orow = outb + (size_t)row * 768;
  orow[t]       = (bf16_t)((v0 - mu) * rs * gamma[t]       + beta[t]);
  orow[t + 256] = (bf16_t)((v1 - mu) * rs * gamma[t + 256] + beta[t + 256]);
  orow[t + 512] = (bf16_t)((v2 - mu) * rs * gamma[t + 512] + beta[t + 512]);
}

// ---------------------------------------------------------------------------
// GEMM: C[M,N] = A[M,K] @ Bt[N,K]^T. 128x128 tile, BK=64, 4 waves (64x64).
// XOR-swizzled LDS (128B rows), XCD-chunked block swizzle, LDS-bounce epilogue.
// ---------------------------------------------------------------------------
template <bool RELU, bool OUT_F32, bool HAS_BIAS, bool HAS_RES>
__global__ __launch_bounds__(256) void gemm_kernel(
    const bf16_t* __restrict__ A, const bf16_t* __restrict__ Bt,
    void* __restrict__ Cout, const float* __restrict__ bias,
    const float* __restrict__ res, int Mdim, int Ndim, int Kdim)
{
  __shared__ __align__(16) bf16_t Smem[2][128 * 64];
  bf16_t* const As = Smem[0];
  bf16_t* const Bs = Smem[1];
  const int tid = threadIdx.x;
  const int lane = tid & 63, w = tid >> 6;
  const int l15 = lane & 15, g = lane >> 4;
  const int gx = gridDim.x;
  const int nwg = gx * gridDim.y;
  const int p = blockIdx.y * gx + blockIdx.x;
  const int wg = (p & 7) * (nwg >> 3) + (p >> 3);
  const int bm = (wg / gx) * 128, bn = (wg % gx) * 128;
  const int wr = (w >> 1) * 64, wc = (w & 1) * 64;
  const int swz = l15 & 7;

  f32x4 acc[4][4] = {};
  const int nK = Kdim >> 6;
  for (int kt = 0; kt < nK; ++kt) {
    const int k0 = kt << 6;
#pragma unroll
    for (int it = 0; it < 4; ++it) {
      const int ch = it * 256 + tid;
      const int r = ch >> 3, c = ch & 7;
      gload16(A + (size_t)(bm + r) * Kdim + k0 + ((c ^ (r & 7)) * 8), As + ch * 8);
    }
#pragma unroll
    for (int it = 0; it < 4; ++it) {
      const int ch = it * 256 + tid;
      const int r = ch >> 3, c = ch & 7;
      gload16(Bt + (size_t)(bn + r) * Kdim + k0 + ((c ^ (r & 7)) * 8), Bs + ch * 8);
    }
    __syncthreads();
#pragma unroll
    for (int kk = 0; kk < 2; ++kk) {
      bf16x8 af[4], bfr[4];
#pragma unroll
      for (int i = 0; i < 4; ++i)
        af[i] = *(const bf16x8*)(As + (wr + i * 16 + l15) * 64 +
                                 (((kk * 4 + g) ^ swz) * 8));
#pragma unroll
      for (int j = 0; j < 4; ++j)
        bfr[j] = *(const bf16x8*)(Bs + (wc + j * 16 + l15) * 64 +
                                  (((kk * 4 + g) ^ swz) * 8));
#pragma unroll
      for (int i = 0; i < 4; ++i)
#pragma unroll
        for (int j = 0; j < 4; ++j)
          acc[i][j] = mfma16(af[i], bfr[j], acc[i][j]);
    }
    __syncthreads();
  }

  // ---- epilogue: LDS bounce (wave-private 8KB) -> vectorized stores ----
  if constexpr (!OUT_F32) {
    bf16_t* const wb = &Smem[0][0] + w * 4096;   // bf16[64][64], chunk-swizzled
#pragma unroll
    for (int i = 0; i < 4; ++i)
#pragma unroll
      for (int j = 0; j < 4; ++j)
#pragma unroll
        for (int r = 0; r < 4; ++r) {
          const int row = i * 16 + g * 4 + r, col = j * 16 + l15;
          float v = acc[i][j][r];
          if constexpr (RELU) v = fmaxf(v, 0.f);
          *(bf16_t*)((char*)wb + row * 128 + ((col * 2) ^ ((row & 7) << 4))) =
              (bf16_t)v;
        }
    __syncthreads();
    bf16_t* const crow0 = (bf16_t*)Cout + (size_t)(bm + wr) * Ndim + bn + wc;
    const int c = lane & 7;
#pragma unroll
    for (int ps = 0; ps < 8; ++ps) {
      const int row = (lane >> 3) + ps * 8;
      bf16x8 v = *(const bf16x8*)((char*)wb + row * 128 +
                                  ((c * 16) ^ ((row & 7) << 4)));
      *(bf16x8*)(crow0 + (size_t)row * Ndim + c * 8) = v;
    }
  } else {
    float* const fb = (float*)&Smem[0][0] + w * 2048;  // f32[64][32], swizzled
    const int c = lane & 7;
#pragma unroll
    for (int jh = 0; jh < 2; ++jh) {
      if (jh) __syncthreads();
#pragma unroll
      for (int i = 0; i < 4; ++i)
#pragma unroll
        for (int jj = 0; jj < 2; ++jj)
#pragma unroll
          for (int r = 0; r < 4; ++r) {
            const int row = i * 16 + g * 4 + r, col = jj * 16 + l15;
            *(float*)((char*)fb + row * 128 + ((col * 4) ^ ((row & 7) << 4))) =
                acc[i][jh * 2 + jj][r];
          }
      __syncthreads();
      const int gcol = bn + wc + jh * 32 + c * 4;
      float4 bv = {0.f, 0.f, 0.f, 0.f};
      if constexpr (HAS_BIAS) bv = *(const float4*)(bias + gcol);
#pragma unroll
      for (int ps = 0; ps < 8; ++ps) {
        const int row = (lane >> 3) + ps * 8;
        float4 v = *(const float4*)((char*)fb + row * 128 +
                                    ((c * 16) ^ ((row & 7) << 4)));
        if constexpr (HAS_BIAS) { v.x += bv.x; v.y += bv.y; v.z += bv.z; v.w += bv.w; }
        if constexpr (HAS_RES) {
          const float4 rv = *(const float4*)(res + (size_t)(bm + wr + row) * Ndim + gcol);
          v.x += rv.x; v.y += rv.y; v.z += rv.z; v.w += rv.w;
        }
        *(float4*)((float*)Cout + (size_t)(bm + wr + row) * Ndim + gcol) = v;
      }
    }
  }
}

// ---------------------------------------------------------------------------
// V transpose: qkv v-columns -> vT[(bh*64+d)][s]
// ---------------------------------------------------------------------------
__global__ __launch_bounds__(256) void transpose_v(
    const bf16_t* __restrict__ qkv, bf16_t* __restrict__ vT)
{
  __shared__ bf16_t t[64][66];
  const int st = blockIdx.x;
  const int bh = blockIdx.y;
  const int b = bh / 12, h = bh % 12;
  const int tid = threadIdx.x;
#pragma unroll
  for (int it = 0; it < 2; ++it) {
    const int ch = it * 256 + tid;
    const int r = ch >> 3, c = ch & 7;
    bf16x8 vv = *(const bf16x8*)(qkv + (size_t)(b * 2048 + st * 64 + r) * 2304 +
                                 1536 + h * 64 + c * 8);
#pragma unroll
    for (int j = 0; j < 8; ++j) t[r][c * 8 + j] = vv[j];
  }
  __syncthreads();
#pragma unroll
  for (int it = 0; it < 2; ++it) {
    const int ch = it * 256 + tid;
    const int d = ch >> 3, c = ch & 7;
    bf16x8 o;
#pragma unroll
    for (int j = 0; j < 8; ++j) o[j] = t[c * 8 + j][d];
    *(bf16x8*)(vT + (size_t)(bh * 64 + d) * 2048 + st * 64 + c * 8) = o;
  }
}

// ---------------------------------------------------------------------------
// Flash attention, 32x32 MFMA, KVBLK=64. Block = (bh, qt), 4 waves x 32 q.
// Lane (q=lane&31, hi=lane>>5). Softmax: raw-score max (mask folded into the
// exp pass as cndmask-to-0), defer-max rescale (THR=8). P -> PV B-frags via
// pk2 + v_permlane32_swap_b32. K/V double-buffered LDS, 1 barrier/kt.
// ---------------------------------------------------------------------------
__global__ __launch_bounds__(256, 4) void attn_kernel(
    const bf16_t* __restrict__ qkv, const bf16_t* __restrict__ vT,
    const unsigned int* __restrict__ mbits, bf16_t* __restrict__ ctx)
{
  __shared__ __align__(16) bf16_t KsBuf[2][64 * 64];   // [s=64][d=64] swizzled
  __shared__ __align__(16) bf16_t VsBuf[2][64 * 64];   // [d=64][s=64] swizzled
  const int tid = threadIdx.x;
  const int lane = tid & 63, w = tid >> 6;
  const int q32 = lane & 31, hi = lane >> 5;
  const int bh = blockIdx.x;      // bh-major => XCD = bh % 8 (K/V L2 affinity)
  const int qt = blockIdx.y;
  const int b = bh / 12, h = bh % 12;
  const int qrow0 = qt * 128 + w * 32;
  const int qabs = qrow0 + q32;

  bf16x8 qf[4];
#pragma unroll
  for (int c = 0; c < 4; ++c)
    qf[c] = *(const bf16x8*)(qkv + (size_t)(b * 2048 + qabs) * 2304 +
                             h * 64 + c * 16 + hi * 8);

  auto stage = [&](bf16_t* ks, bf16_t* vs, int kt) {
    const size_t kb0 = (size_t)(b * 2048 + kt * 64);
#pragma unroll
    for (int it = 0; it < 2; ++it) {
      const int ch = it * 256 + tid;       // 0..511: K row s, 16B chunk (d)
      const int r = ch >> 3, c = ch & 7;
      gload16(qkv + (kb0 + r) * 2304 + 768 + h * 64 + ((c ^ (r & 7)) * 8), ks + ch * 8);
    }
#pragma unroll
    for (int it = 0; it < 2; ++it) {
      const int ch = it * 256 + tid;       // 0..511: V^T row d, 16B chunk (s)
      const int r = ch >> 3, c = ch & 7;
      gload16(vT + (size_t)(bh * 64 + r) * 2048 + kt * 64 + ((c ^ (r & 7)) * 8),
              vs + ch * 8);
    }
  };

  f32x16 oacc[2] = {};
  float mrun = NEGF, lrun = 0.f;

  stage(KsBuf[0], VsBuf[0], 0);
  __syncthreads();

  for (int kt = 0; kt < 32; ++kt) {
    const bf16_t* ksc = (kt & 1) ? KsBuf[1] : KsBuf[0];
    const bf16_t* vsc = (kt & 1) ? VsBuf[1] : VsBuf[0];
    if (kt < 31)
      stage((kt & 1) ? KsBuf[0] : KsBuf[1], (kt & 1) ? VsBuf[0] : VsBuf[1], kt + 1);

    const uint2 mm = *(const uint2*)(mbits + (size_t)(b * 2048 + qabs) * 64 + kt * 2);
    const unsigned mwv[2] = {mm.x >> (hi * 4), mm.y >> (hi * 4)};

    // ---- S^T = K @ Q^T from LDS: sacc[kb] = 32k x 32q tile ----
    f32x16 sacc[2] = {};
#pragma unroll
    for (int c = 0; c < 4; ++c) {
#pragma unroll
      for (int kb = 0; kb < 2; ++kb) {
        const int row = kb * 32 + q32;
        const int slot = (2 * c + hi) ^ (row & 7);
        bf16x8 kf = *(const bf16x8*)(ksc + row * 64 + slot * 8);
        sacc[kb] = mfma32(kf, qf[c], sacc[kb]);
      }
    }

    // ---- raw-score max (mask deferred to exp pass; over-max cancels) ----
    float rmax = NEGF;
#pragma unroll
    for (int kb = 0; kb < 2; ++kb)
#pragma unroll
      for (int i = 0; i < 16; ++i) rmax = fmaxf(rmax, sacc[kb][i]);
    rmax = fmaxf(rmax, __shfl_xor(rmax, 32, 64));
    if (!__all(rmax - mrun <= 8.f)) {      // defer-max: rescale only on growth
      const float mn = fmaxf(mrun, rmax);
      const float sc = exp2_fast(mrun - mn);
      lrun *= sc;
      oacc[0] *= sc;
      oacc[1] *= sc;
      mrun = mn;
    }
    // ---- exp + mask-to-zero + sum ----
    float ps = 0.f;
#pragma unroll
    for (int kb = 0; kb < 2; ++kb) {
#pragma unroll
      for (int rq = 0; rq < 4; ++rq) {
        const unsigned sel = mwv[kb] >> (8 * rq);
#pragma unroll
        for (int i = 0; i < 4; ++i) {
          const float e = exp2_fast(sacc[kb][rq * 4 + i] - mrun);
          const float p = ((sel >> i) & 1u) ? 0.f : e;
          sacc[kb][rq * 4 + i] = p;
          ps += p;
        }
      }
    }
    ps += __shfl_xor(ps, 32, 64);
    lrun += ps;

    // ---- PV: O^T += V^T @ P, P frags via permlane32_swap ----
#pragma unroll
    for (int kb = 0; kb < 2; ++kb) {
      unsigned u0 = pk2(sacc[kb][0],  sacc[kb][1]);
      unsigned u1 = pk2(sacc[kb][2],  sacc[kb][3]);
      unsigned u2 = pk2(sacc[kb][4],  sacc[kb][5]);
      unsigned u3 = pk2(sacc[kb][6],  sacc[kb][7]);
      unsigned u4 = pk2(sacc[kb][8],  sacc[kb][9]);
      unsigned u5 = pk2(sacc[kb][10], sacc[kb][11]);
      unsigned u6 = pk2(sacc[kb][12], sacc[kb][13]);
      unsigned u7 = pk2(sacc[kb][14], sacc[kb][15]);
      pl32_swap(u0, u2);  pl32_swap(u1, u3);
      pl32_swap(u4, u6);  pl32_swap(u5, u7);
      bf16x8 p0 = frag4(u0, u1, u2, u3);
      bf16x8 p1 = frag4(u4, u5, u6, u7);
#pragma unroll
      for (int ks = 0; ks < 2; ++ks) {
        const bf16x8 pf = ks ? p1 : p0;
        const int cg = kb * 4 + ks * 2 + hi;   // 0..7
#pragma unroll
        for (int dt = 0; dt < 2; ++dt) {
          const int row = dt * 32 + q32;
          bf16x8 vf = *(const bf16x8*)(vsc + row * 64 + ((cg ^ (row & 7)) * 8));
          oacc[dt] = mfma32(vf, pf, oacc[dt]);
        }
      }
    }
    __syncthreads();
  }

  const float inv = (lrun > 0.f) ? 1.f / lrun : 0.f;
  bf16_t* crow = ctx + (size_t)(b * 2048 + qabs) * 768 + h * 64;
#pragma unroll
  for (int dt = 0; dt < 2; ++dt)
#pragma unroll
    for (int rq = 0; rq < 4; ++rq) {
      bf16x4 ov = {(bf16_t)(oacc[dt][rq * 4 + 0] * inv),
                   (bf16_t)(oacc[dt][rq * 4 + 1] * inv),
                   (bf16_t)(oacc[dt][rq * 4 + 2] * inv),
                   (bf16_t)(oacc[dt][rq * 4 + 3] * inv)};
      *(bf16x4*)(crow + dt * 32 + rq * 8 + hi * 4) = ov;
    }
}

// ---------------------------------------------------------------------------
// Host launcher
// ---------------------------------------------------------------------------
extern "C" void kernel_launch(void* const* d_in, const int* in_sizes, int n_in,
                              void* d_out, int out_size, void* d_ws, size_t ws_size,
                              hipStream_t stream) {
  const float* x  = (const float*)d_in[0];
  const int* mask = (const int*)d_in[1];
  const float* wq = (const float*)d_in[2];
  const float* wk = (const float*)d_in[3];
  const float* wv = (const float*)d_in[4];
  const float* wo = (const float*)d_in[5];
  const float* bo = (const float*)d_in[6];
  const float* w1 = (const float*)d_in[7];
  const float* w2 = (const float*)d_in[8];
  const float* g1 = (const float*)d_in[9];
  const float* b1 = (const float*)d_in[10];
  const float* g2 = (const float*)d_in[11];
  const float* b2 = (const float*)d_in[12];
  float* out = (float*)d_out;

  char* p = (char*)d_ws;
  bf16_t* WQKVT = (bf16_t*)p; p += (size_t)2304 * 768 * 2;
  bf16_t* WOT   = (bf16_t*)p; p += (size_t)768 * 768 * 2;
  bf16_t* W1T   = (bf16_t*)p; p += (size_t)3072 * 768 * 2;
  bf16_t* W2T   = (bf16_t*)p; p += (size_t)768 * 3072 * 2;
  unsigned int* MB = (unsigned int*)p; p += (size_t)4 * 2048 * 64 * 4;
  bf16_t* Hbuf  = (bf16_t*)p; p += (size_t)8192 * 768 * 2;
  float*  X2    = (float*)p;  p += (size_t)8192 * 768 * 4;
  bf16_t* QKV   = (bf16_t*)p; p += (size_t)8192 * 2304 * 2;
  bf16_t* CTX   = (bf16_t*)p;
  bf16_t* FFN   = QKV;
  bf16_t* VT    = Hbuf;

  const dim3 tb(32, 8);
  // wq carries 1/sqrt(DH) * log2(e) so softmax runs in exp2 domain
  transpose_conv<<<dim3(24, 24), tb, 0, stream>>>(wq, WQKVT,              768, 768, 0.125f * LOG2E);
  transpose_conv<<<dim3(24, 24), tb, 0, stream>>>(wk, WQKVT + 768 * 768,  768, 768, 1.f);
  transpose_conv<<<dim3(24, 24), tb, 0, stream>>>(wv, WQKVT + 1536 * 768, 768, 768, 1.f);
  transpose_conv<<<dim3(24, 24), tb, 0, stream>>>(wo, WOT, 768, 768, 1.f);
  transpose_conv<<<dim3(96, 24), tb, 0, stream>>>(w1, W1T, 768, 3072, 1.f);
  transpose_conv<<<dim3(24, 96), tb, 0, stream>>>(w2, W2T, 3072, 768, 1.f);
  pack_mask<<<65536, 256, 0, stream>>>(mask, MB);

  ln_kernel<<<8192, 256, 0, stream>>>(x, g1, b1, Hbuf);
  gemm_kernel<false, false, false, false><<<dim3(18, 64), 256, 0, stream>>>(
      Hbuf, WQKVT, QKV, nullptr, nullptr, 8192, 2304, 768);
  transpose_v<<<dim3(32, 48), 256, 0, stream>>>(QKV, VT);
  attn_kernel<<<dim3(48, 16), 256, 0, stream>>>(QKV, VT, MB, CTX);
  gemm_kernel<false, true, true, true><<<dim3(6, 64), 256, 0, stream>>>(
      CTX, WOT, X2, bo, x, 8192, 768, 768);

  ln_kernel<<<8192, 256, 0, stream>>>(X2, g2, b2, Hbuf);
  gemm_kernel<true, false, false, false><<<dim3(24, 64), 256, 0, stream>>>(
      Hbuf, W1T, FFN, nullptr, nullptr, 8192, 3072, 768);
  gemm_kernel<false, true, false, true><<<dim3(6, 64), 256, 0, stream>>>(
      FFN, W2T, out, nullptr, X2, 8192, 768, 3072);
}